// Round 6
// baseline (400.109 us; speedup 1.0000x reference)
//
#include <hip/hip_runtime.h>
#include <cfloat>

#define PIXB 1024
static const size_t OFF_Z = 6291456;   // recon = 32*3*256*256
static const size_t OFF_E = 23068672;  // OFF_Z + 32*512*32*32
static const size_t OFF_A = 39845888;  // OFF_E + 32*512*32*32

typedef _Float16 f16x8 __attribute__((ext_vector_type(8)));
typedef _Float16 f16x4 __attribute__((ext_vector_type(4)));
typedef float f32x16 __attribute__((ext_vector_type(16)));

#define SPLIT_SCALE 4096.0f
#define SPLIT_INV   (1.0f / 4096.0f)

// ---------------- prep: Wq[c][d] fp16 splits (transposed codebook) + w2 -----
// Wq: [code 512][d 512] per split, splits at +262144 halves. 1MB total, lives
// in the recon region of d_out (overwritten later by k_decode). L2-resident.
__global__ __launch_bounds__(256) void k_prep(const float* __restrict__ W,
                                              _Float16* __restrict__ wq,
                                              float* __restrict__ w2) {
  const int t = threadIdx.x;
  if (blockIdx.x == 8) {
    if (blockIdx.y < 2) {
      const int k = blockIdx.y * 256 + t;
      float acc = 0.f;
      for (int d = 0; d < 512; ++d) { const float v = W[(size_t)d * 512 + k]; acc = fmaf(v, v, acc); }
      w2[k] = acc;
    }
    return;
  }
  __shared__ float T[64][65];
  const int c0 = blockIdx.x * 64, d0 = blockIdx.y * 64;
#pragma unroll
  for (int i = 0; i < 16; ++i) {
    const int dl = i * 4 + (t >> 6);
    T[dl][t & 63] = W[(size_t)(d0 + dl) * 512 + c0 + (t & 63)];
  }
  __syncthreads();
#pragma unroll
  for (int i = 0; i < 16; ++i) {
    const int cl = i * 4 + (t >> 6);
    const int dl = t & 63;
    const float v = T[dl][cl];
    const _Float16 h = (_Float16)v;
    const _Float16 l = (_Float16)((v - (float)h) * SPLIT_SCALE);
    wq[(size_t)(c0 + cl) * 512 + d0 + dl] = h;
    wq[262144 + (size_t)(c0 + cl) * 512 + d0 + dl] = l;
  }
}

// ---------------- encode: z_e = conv(x) + b, as GEMM 512x192 @ 192x32768 ----
// also emits zq: fp16-split z in [pix][d] layout (OFF_E region scratch; the
// emb output overwrites it later via k_gather).
__global__ __launch_bounds__(256) void k_encode(const float* __restrict__ x,
                                                const float* __restrict__ ew,
                                                const float* __restrict__ eb,
                                                _Float16* __restrict__ zqh,
                                                float* __restrict__ out) {
  __shared__ __align__(16) float Ps[16][68];
  __shared__ __align__(16) float Ws[16][68];
  const int n0 = blockIdx.x * 64;
  const int b = n0 / PIXB;
  const int pixbase = n0 % PIXB;
  const int i0 = pixbase >> 5;
  const int c0 = blockIdx.y * 64;
  const int t = threadIdx.x;
  const int tx = t & 15, ty = t >> 4;
  float acc[4][4];
#pragma unroll
  for (int m = 0; m < 4; ++m)
#pragma unroll
    for (int p = 0; p < 4; ++p) acc[m][p] = 0.f;

  const int jj = t >> 3, kjj = t & 7;
  for (int kc = 0; kc < 12; ++kc) {
    const int ci = kc >> 2, kip = kc & 3;
#pragma unroll
    for (int rr = 0; rr < 4; ++rr) {
      const int di = rr >> 1, dki = rr & 1;
      const int row = (i0 + di) * 8 + kip * 2 + dki;
      const float v = x[(((size_t)b * 3 + ci) * 256 + row) * 256 + t];
      Ps[dki * 8 + kjj][di * 32 + jj] = v;
    }
    const int k0 = kc * 16;
#pragma unroll
    for (int ii = 0; ii < 4; ++ii) {
      const int idx = t + ii * 256;
      const int cc = idx >> 4, kk = idx & 15;
      Ws[kk][cc] = ew[(size_t)(c0 + cc) * 192 + k0 + kk];
    }
    __syncthreads();
#pragma unroll
    for (int kk = 0; kk < 16; ++kk) {
      const float4 av = *reinterpret_cast<const float4*>(&Ws[kk][ty * 4]);
      const float4 bv = *reinterpret_cast<const float4*>(&Ps[kk][tx * 4]);
      const float a[4] = {av.x, av.y, av.z, av.w};
      const float bb[4] = {bv.x, bv.y, bv.z, bv.w};
#pragma unroll
      for (int m = 0; m < 4; ++m)
#pragma unroll
        for (int p = 0; p < 4; ++p) acc[m][p] = fmaf(a[m], bb[p], acc[m][p]);
    }
    __syncthreads();
  }
  float zf[4][4];
#pragma unroll
  for (int m = 0; m < 4; ++m) {
    const int c = c0 + ty * 4 + m;
    const float bias = eb[c];
#pragma unroll
    for (int p = 0; p < 4; ++p) zf[m][p] = acc[m][p] + bias;
    float4 v;
    v.x = zf[m][0]; v.y = zf[m][1]; v.z = zf[m][2]; v.w = zf[m][3];
    *reinterpret_cast<float4*>(&out[OFF_Z + ((size_t)b * 512 + c) * 1024 + pixbase + tx * 4]) = v;
  }
#pragma unroll
  for (int p = 0; p < 4; ++p) {
    const int pix = pixbase + tx * 4 + p;
    f16x4 hv, lv;
#pragma unroll
    for (int m = 0; m < 4; ++m) {
      const float f = zf[m][p];
      const _Float16 h = (_Float16)f;
      hv[m] = h;
      lv[m] = (_Float16)((f - (float)h) * SPLIT_SCALE);
    }
    _Float16* zp = zqh + ((size_t)(b * 1024) + pix) * 512 + c0 + ty * 4;
    *(f16x4*)zp = hv;
    *(f16x4*)(zp + 16777216) = lv;
  }
}

// -------- distance + argmin via MFMA, barrier-free reg-resident main loop ---
// Block: 64 pixels x 512 codes, 8 waves (wc = w&3 codes, wp = w>>2 pixels).
// All operands loaded k-contiguous from L2-resident global (Wq, zq) straight
// to registers; no LDS, no syncthreads, no vmcnt(0) in the main loop.
// z2 omitted: it is a per-pixel constant shift, argmin-invariant (near-tie
// rounding perturbation ~1 ulp, smaller than the fp16-split error already
// validated in rounds 1-5). d2' = w2 - 2*(accA + accB/4096).
__global__ __launch_bounds__(512) void k_dist(const _Float16* __restrict__ wq,
                                              const _Float16* __restrict__ zq,
                                              const float* __restrict__ w2ws,
                                              float* __restrict__ out) {
  __shared__ float w2L[512];
  __shared__ float WV[512];
  __shared__ int   WI[512];
  const int t = threadIdx.x;
  w2L[t] = w2ws[t];
  const int w = t >> 6, lane = t & 63;
  const int wc = w & 3, wp = w >> 2;
  const int n0 = blockIdx.x * 64;
  const int b = n0 >> 10, pixbase = n0 & 1023;
  const int kl = (lane >> 5) * 8;        // k-offset in halves
  const int row = lane & 31;

  const _Float16* ah[4];
  const _Float16* al[4];
#pragma unroll
  for (int ct = 0; ct < 4; ++ct) {
    ah[ct] = wq + (size_t)(wc * 128 + ct * 32 + row) * 512 + kl;
    al[ct] = ah[ct] + 262144;
  }
  const _Float16* zh = zq + ((size_t)(b * 1024) + pixbase + wp * 32 + row) * 512 + kl;
  const _Float16* zl = zh + 16777216;

  f32x16 accA[4], accB[4];
#pragma unroll
  for (int ct = 0; ct < 4; ++ct) { accA[ct] = (f32x16)(0.0f); accB[ct] = (f32x16)(0.0f); }

#pragma unroll 1
  for (int ch = 0; ch < 16; ++ch) {
    const f16x8 Bh0 = *(const f16x8*)(zh);
    const f16x8 Bh1 = *(const f16x8*)(zh + 16);
    const f16x8 Bl0 = *(const f16x8*)(zl);
    const f16x8 Bl1 = *(const f16x8*)(zl + 16);
#pragma unroll
    for (int ct = 0; ct < 4; ++ct) {
      const f16x8 Ah0 = *(const f16x8*)(ah[ct]);
      const f16x8 Ah1 = *(const f16x8*)(ah[ct] + 16);
      const f16x8 Al0 = *(const f16x8*)(al[ct]);
      const f16x8 Al1 = *(const f16x8*)(al[ct] + 16);
      accA[ct] = __builtin_amdgcn_mfma_f32_32x32x16_f16(Ah0, Bh0, accA[ct], 0, 0, 0);
      accB[ct] = __builtin_amdgcn_mfma_f32_32x32x16_f16(Ah0, Bl0, accB[ct], 0, 0, 0);
      accB[ct] = __builtin_amdgcn_mfma_f32_32x32x16_f16(Al0, Bh0, accB[ct], 0, 0, 0);
      accA[ct] = __builtin_amdgcn_mfma_f32_32x32x16_f16(Ah1, Bh1, accA[ct], 0, 0, 0);
      accB[ct] = __builtin_amdgcn_mfma_f32_32x32x16_f16(Ah1, Bl1, accB[ct], 0, 0, 0);
      accB[ct] = __builtin_amdgcn_mfma_f32_32x32x16_f16(Al1, Bh1, accB[ct], 0, 0, 0);
      ah[ct] += 32; al[ct] += 32;
    }
    zh += 32; zl += 32;
  }

  __syncthreads();   // w2L visibility (written at kernel start)

  // ---- per-lane d2 + argmin over its 128 codes ----
  // C/D layout (32x32): col = lane&31 (pixel), row = (r&3)+8*(r>>2)+4*(lane>>5)
  float bv = FLT_MAX; int bi = 0x7fffffff;
#pragma unroll
  for (int ct = 0; ct < 4; ++ct) {
#pragma unroll
    for (int r = 0; r < 16; ++r) {
      const int code = wc * 128 + ct * 32 + ((r & 3) + ((r >> 2) << 3) + ((lane >> 5) << 2));
      const float zw = fmaf(accB[ct][r], SPLIT_INV, accA[ct][r]);
      const float d2 = fmaf(-2.f, zw, w2L[code]);
      if (d2 < bv || (d2 == bv && code < bi)) { bv = d2; bi = code; }
    }
  }
  WV[w * 64 + lane] = bv;
  WI[w * 64 + lane] = bi;
  __syncthreads();

  // ---- final per-pixel reduce (8 candidates), write argmin ----
  if (t < 64) {
    const int pw = t >> 5;
    float fbv = FLT_MAX; int fbi = 0x7fffffff;
#pragma unroll
    for (int wcc = 0; wcc < 4; ++wcc)
#pragma unroll
      for (int hh = 0; hh < 2; ++hh) {
        const int li = (pw * 4 + wcc) * 64 + (t & 31) + hh * 32;
        const float v = WV[li];
        const int ii = WI[li];
        if (v < fbv || (v == fbv && ii < fbi)) { fbv = v; fbi = ii; }
      }
    out[OFF_A + n0 + t] = (float)fbi;
  }
}

// ---------------- gather: emb[d][pix] = W[d][argmin[pix]] -------------------
// runs AFTER k_dist (zq scratch in the OFF_E region is dead by then).
__global__ __launch_bounds__(256) void k_gather(const float* __restrict__ Wc,
                                                float* __restrict__ out) {
  const int n0 = blockIdx.x * 32;
  const int b = n0 >> 10, pixbase = n0 & 1023;
  const int t = threadIdx.x;
  const int pix = t & 31;
  const int kidx = (int)out[OFF_A + n0 + pix];
  for (int d = t >> 5; d < 512; d += 8)
    out[OFF_E + ((size_t)(b * 512 + d)) * 1024 + pixbase + pix] = Wc[(size_t)d * 512 + kidx];
}

// ---------------- decode: conv_transpose (kernel spatially FLIPPED) ---------
__global__ __launch_bounds__(256) void k_decode(const float* __restrict__ dw,
                                                const float* __restrict__ db,
                                                float* out) {
  __shared__ __align__(16) float Qs[32][132];
  __shared__ __align__(16) float Ws3[32][68];
  const int n0 = blockIdx.x * 128;
  const int b = n0 / PIXB, pixbase = n0 % PIXB;
  const int mt = blockIdx.y;
  const int t = threadIdx.x;
  const int pg = t & 31, ck = t >> 5;
  float acc[4][8];
#pragma unroll
  for (int p = 0; p < 4; ++p)
#pragma unroll
    for (int k = 0; k < 8; ++k) acc[p][k] = 0.f;
  for (int dc = 0; dc < 16; ++dc) {
#pragma unroll
    for (int ii = 0; ii < 4; ++ii) {
      const int id = t + ii * 256;
      const int dd = id >> 5, p4 = id & 31;
      *reinterpret_cast<float4*>(&Qs[dd][p4 * 4]) =
        *reinterpret_cast<const float4*>(&out[OFF_E + ((size_t)b * 512 + dc * 32 + dd) * 1024 + pixbase + p4 * 4]);
    }
#pragma unroll
    for (int ii = 0; ii < 2; ++ii) {
      const int id = t + ii * 256;
      const int dd = id >> 4, m4 = id & 15;
      *reinterpret_cast<float4*>(&Ws3[dd][m4 * 4]) =
        *reinterpret_cast<const float4*>(&dw[(size_t)(dc * 32 + dd) * 192 + mt * 64 + m4 * 4]);
    }
    __syncthreads();
#pragma unroll
    for (int dd = 0; dd < 32; ++dd) {
      const float4 qv = *reinterpret_cast<const float4*>(&Qs[dd][pg * 4]);
      const float4 wa = *reinterpret_cast<const float4*>(&Ws3[dd][ck * 8]);
      const float4 wb = *reinterpret_cast<const float4*>(&Ws3[dd][ck * 8 + 4]);
      const float q[4] = {qv.x, qv.y, qv.z, qv.w};
      const float w[8] = {wa.x, wa.y, wa.z, wa.w, wb.x, wb.y, wb.z, wb.w};
#pragma unroll
      for (int p = 0; p < 4; ++p)
#pragma unroll
        for (int k = 0; k < 8; ++k) acc[p][k] = fmaf(q[p], w[k], acc[p][k]);
    }
    __syncthreads();
  }
  const int ckg = mt * 8 + ck;
  const int c = ckg >> 3, ki = ckg & 7;
  const float bias = db[c];
#pragma unroll
  for (int p = 0; p < 4; ++p) {
    const int pix = pixbase + pg * 4 + p;
    const int i = pix >> 5, j = pix & 31;
    const size_t base = (((size_t)b * 3 + c) * 256 + i * 8 + 7 - ki) * 256 + j * 8;
#pragma unroll
    for (int kj = 0; kj < 8; ++kj) out[base + 7 - kj] = acc[p][kj] + bias;
  }
}

extern "C" void kernel_launch(void* const* d_in, const int* in_sizes, int n_in,
                              void* d_out, int out_size, void* d_ws, size_t ws_size,
                              hipStream_t stream) {
  const float* x     = (const float*)d_in[0];
  const float* enc_w = (const float*)d_in[1];
  const float* enc_b = (const float*)d_in[2];
  const float* dec_w = (const float*)d_in[3];
  const float* dec_b = (const float*)d_in[4];
  const float* emb_w = (const float*)d_in[5];
  float* out = (float*)d_out;
  float* w2 = (float*)d_ws;                          // 512 floats
  _Float16* wq  = (_Float16*)d_out;                  // 1MB in recon region (overwritten by k_decode)
  _Float16* zqh = (_Float16*)((char*)d_out + 92274688);  // OFF_E*4: zq splits (67.1MB, exact region fit)

  k_prep<<<dim3(9, 8), 256, 0, stream>>>(emb_w, wq, w2);
  k_encode<<<dim3(512, 8), 256, 0, stream>>>(x, enc_w, enc_b, zqh, out);
  k_dist<<<512, 512, 0, stream>>>(wq, zqh, w2, out);
  k_gather<<<1024, 256, 0, stream>>>(emb_w, out);
  k_decode<<<dim3(256, 3), 256, 0, stream>>>(dec_w, dec_b, out);
}

// Round 7
// 392.800 us; speedup vs baseline: 1.0186x; 1.0186x over previous
//
#include <hip/hip_runtime.h>
#include <cfloat>

#define PIXB 1024
static const size_t OFF_Z = 6291456;   // recon = 32*3*256*256
static const size_t OFF_E = 23068672;  // OFF_Z + 32*512*32*32
static const size_t OFF_A = 39845888;  // OFF_E + 32*512*32*32

typedef _Float16 f16x8 __attribute__((ext_vector_type(8)));
typedef _Float16 f16x4 __attribute__((ext_vector_type(4)));
typedef float f32x16 __attribute__((ext_vector_type(16)));

#define SPLIT_SCALE 4096.0f
#define SPLIT_INV   (1.0f / 4096.0f)

// ---------------- prep: Wq[c][d] fp16 splits (transposed codebook) + w2 -----
// Wq: [code 512][d 512] per split, splits at +262144 halves. 1MB total, lives
// in the recon region of d_out (overwritten later by k_decode). L2-resident.
__global__ __launch_bounds__(256) void k_prep(const float* __restrict__ W,
                                              _Float16* __restrict__ wq,
                                              float* __restrict__ w2) {
  const int t = threadIdx.x;
  if (blockIdx.x == 8) {
    if (blockIdx.y < 2) {
      const int k = blockIdx.y * 256 + t;
      float acc = 0.f;
      for (int d = 0; d < 512; ++d) { const float v = W[(size_t)d * 512 + k]; acc = fmaf(v, v, acc); }
      w2[k] = acc;
    }
    return;
  }
  __shared__ float T[64][65];
  const int c0 = blockIdx.x * 64, d0 = blockIdx.y * 64;
#pragma unroll
  for (int i = 0; i < 16; ++i) {
    const int dl = i * 4 + (t >> 6);
    T[dl][t & 63] = W[(size_t)(d0 + dl) * 512 + c0 + (t & 63)];
  }
  __syncthreads();
#pragma unroll
  for (int i = 0; i < 16; ++i) {
    const int cl = i * 4 + (t >> 6);
    const int dl = t & 63;
    const float v = T[dl][cl];
    const _Float16 h = (_Float16)v;
    const _Float16 l = (_Float16)((v - (float)h) * SPLIT_SCALE);
    wq[(size_t)(c0 + cl) * 512 + d0 + dl] = h;
    wq[262144 + (size_t)(c0 + cl) * 512 + d0 + dl] = l;
  }
}

// ---------------- encode: z_e = conv(x) + b, as GEMM 512x192 @ 192x32768 ----
// also emits zq (fp16 splits, [pix][d] layout) via LDS transpose so the
// global stores are contiguous 64B segments (round 6 scattered 8B stores).
__global__ __launch_bounds__(256) void k_encode(const float* __restrict__ x,
                                                const float* __restrict__ ew,
                                                const float* __restrict__ eb,
                                                _Float16* __restrict__ zqh,
                                                float* __restrict__ out) {
  __shared__ __align__(16) float Ps[16][68];
  __shared__ __align__(16) float Ws[16][68];
  __shared__ __align__(16) _Float16 ZT[64][80];   // 10KB transpose buffer
  const int n0 = blockIdx.x * 64;
  const int b = n0 / PIXB;
  const int pixbase = n0 % PIXB;
  const int i0 = pixbase >> 5;
  const int c0 = blockIdx.y * 64;
  const int t = threadIdx.x;
  const int tx = t & 15, ty = t >> 4;
  float acc[4][4];
#pragma unroll
  for (int m = 0; m < 4; ++m)
#pragma unroll
    for (int p = 0; p < 4; ++p) acc[m][p] = 0.f;

  const int jj = t >> 3, kjj = t & 7;
  for (int kc = 0; kc < 12; ++kc) {
    const int ci = kc >> 2, kip = kc & 3;
#pragma unroll
    for (int rr = 0; rr < 4; ++rr) {
      const int di = rr >> 1, dki = rr & 1;
      const int row = (i0 + di) * 8 + kip * 2 + dki;
      const float v = x[(((size_t)b * 3 + ci) * 256 + row) * 256 + t];
      Ps[dki * 8 + kjj][di * 32 + jj] = v;
    }
    const int k0 = kc * 16;
#pragma unroll
    for (int ii = 0; ii < 4; ++ii) {
      const int idx = t + ii * 256;
      const int cc = idx >> 4, kk = idx & 15;
      Ws[kk][cc] = ew[(size_t)(c0 + cc) * 192 + k0 + kk];
    }
    __syncthreads();
#pragma unroll
    for (int kk = 0; kk < 16; ++kk) {
      const float4 av = *reinterpret_cast<const float4*>(&Ws[kk][ty * 4]);
      const float4 bv = *reinterpret_cast<const float4*>(&Ps[kk][tx * 4]);
      const float a[4] = {av.x, av.y, av.z, av.w};
      const float bb[4] = {bv.x, bv.y, bv.z, bv.w};
#pragma unroll
      for (int m = 0; m < 4; ++m)
#pragma unroll
        for (int p = 0; p < 4; ++p) acc[m][p] = fmaf(a[m], bb[p], acc[m][p]);
    }
    __syncthreads();
  }
  float zf[4][4];
#pragma unroll
  for (int m = 0; m < 4; ++m) {
    const int c = c0 + ty * 4 + m;
    const float bias = eb[c];
#pragma unroll
    for (int p = 0; p < 4; ++p) zf[m][p] = acc[m][p] + bias;
    float4 v;
    v.x = zf[m][0]; v.y = zf[m][1]; v.z = zf[m][2]; v.w = zf[m][3];
    *reinterpret_cast<float4*>(&out[OFF_Z + ((size_t)b * 512 + c) * 1024 + pixbase + tx * 4]) = v;
  }
  // ---- zq emission: two passes (h, l) through LDS transpose ----
#pragma unroll
  for (int s = 0; s < 2; ++s) {
    __syncthreads();
#pragma unroll
    for (int p = 0; p < 4; ++p) {
      f16x4 v;
#pragma unroll
      for (int m = 0; m < 4; ++m) {
        const float f = zf[m][p];
        const _Float16 h = (_Float16)f;
        v[m] = (s == 0) ? h : (_Float16)((f - (float)h) * SPLIT_SCALE);
      }
      *(f16x4*)&ZT[tx * 4 + p][ty * 4] = v;
    }
    __syncthreads();
    _Float16* dst = zqh + (size_t)s * 16777216 +
                    ((size_t)(b * 1024) + pixbase + (t >> 2)) * 512 + c0;
#pragma unroll
    for (int g = 0; g < 2; ++g) {
      const int seg = (t & 3) + g * 4;
      *(f16x8*)(dst + seg * 8) = *(const f16x8*)&ZT[t >> 2][seg * 8];
    }
  }
}

// -------- distance + argmin via MFMA, fully-unrolled reg-resident loop ------
// Block: 64 pixels x 512 codes, 8 waves (wc = w&3 code slice, wp = w>>2 pixel
// half). All operands loaded k-contiguous from L2-resident global straight to
// registers. FULL unroll + immediate offsets (all chunk addresses = base +
// ch*64B, 13-bit imm): zero loop-carried pointer math, compiler free to
// software-pipeline loads across chunks (round 6's `unroll 1` forbade this ->
// per-chunk L2-latency serialization, MfmaUtil 11.6%).
// z2 omitted (per-pixel constant shift, argmin-invariant). Numerically
// identical op sequence per accumulator to rounds 5/6 (both passed).
__global__ __launch_bounds__(512) void k_dist(const _Float16* __restrict__ wq,
                                              const _Float16* __restrict__ zq,
                                              const float* __restrict__ w2ws,
                                              float* __restrict__ out) {
  __shared__ float w2L[512];
  __shared__ float WV[512];
  __shared__ int   WI[512];
  const int t = threadIdx.x;
  w2L[t] = w2ws[t];
  const int w = t >> 6, lane = t & 63;
  const int wc = w & 3, wp = w >> 2;
  const int n0 = blockIdx.x * 64;
  const int b = n0 >> 10, pixbase = n0 & 1023;
  const int kl = (lane >> 5) * 8;        // k-offset in halves
  const int row = lane & 31;

  const f16x8* ah[4];
  const f16x8* al[4];
#pragma unroll
  for (int ct = 0; ct < 4; ++ct) {
    const _Float16* p = wq + (size_t)(wc * 128 + ct * 32 + row) * 512 + kl;
    ah[ct] = (const f16x8*)p;
    al[ct] = (const f16x8*)(p + 262144);
  }
  const _Float16* zp = zq + ((size_t)(b * 1024) + pixbase + wp * 32 + row) * 512 + kl;
  const f16x8* bh = (const f16x8*)zp;
  const f16x8* bl = (const f16x8*)(zp + 16777216);

  f32x16 accA[4], accB[4];
#pragma unroll
  for (int ct = 0; ct < 4; ++ct) { accA[ct] = (f32x16)(0.0f); accB[ct] = (f32x16)(0.0f); }

#pragma unroll
  for (int ch = 0; ch < 16; ++ch) {
    const f16x8 Bh0 = bh[ch * 4], Bh1 = bh[ch * 4 + 2];
    const f16x8 Bl0 = bl[ch * 4], Bl1 = bl[ch * 4 + 2];
#pragma unroll
    for (int ct = 0; ct < 4; ++ct) {
      const f16x8 Ah0 = ah[ct][ch * 4], Ah1 = ah[ct][ch * 4 + 2];
      const f16x8 Al0 = al[ct][ch * 4], Al1 = al[ct][ch * 4 + 2];
      accA[ct] = __builtin_amdgcn_mfma_f32_32x32x16_f16(Ah0, Bh0, accA[ct], 0, 0, 0);
      accB[ct] = __builtin_amdgcn_mfma_f32_32x32x16_f16(Ah0, Bl0, accB[ct], 0, 0, 0);
      accB[ct] = __builtin_amdgcn_mfma_f32_32x32x16_f16(Al0, Bh0, accB[ct], 0, 0, 0);
      accA[ct] = __builtin_amdgcn_mfma_f32_32x32x16_f16(Ah1, Bh1, accA[ct], 0, 0, 0);
      accB[ct] = __builtin_amdgcn_mfma_f32_32x32x16_f16(Ah1, Bl1, accB[ct], 0, 0, 0);
      accB[ct] = __builtin_amdgcn_mfma_f32_32x32x16_f16(Al1, Bh1, accB[ct], 0, 0, 0);
    }
  }

  __syncthreads();   // w2L visibility

  // ---- per-lane d2 + argmin over its 128 codes ----
  // C/D layout (32x32): col = lane&31 (pixel), row = (r&3)+8*(r>>2)+4*(lane>>5)
  float bv = FLT_MAX; int bi = 0x7fffffff;
#pragma unroll
  for (int ct = 0; ct < 4; ++ct) {
#pragma unroll
    for (int r = 0; r < 16; ++r) {
      const int code = wc * 128 + ct * 32 + ((r & 3) + ((r >> 2) << 3) + ((lane >> 5) << 2));
      const float zw = fmaf(accB[ct][r], SPLIT_INV, accA[ct][r]);
      const float d2 = fmaf(-2.f, zw, w2L[code]);
      if (d2 < bv || (d2 == bv && code < bi)) { bv = d2; bi = code; }
    }
  }
  WV[w * 64 + lane] = bv;
  WI[w * 64 + lane] = bi;
  __syncthreads();

  // ---- final per-pixel reduce (8 candidates), write argmin ----
  if (t < 64) {
    const int pw = t >> 5;
    float fbv = FLT_MAX; int fbi = 0x7fffffff;
#pragma unroll
    for (int wcc = 0; wcc < 4; ++wcc)
#pragma unroll
      for (int hh = 0; hh < 2; ++hh) {
        const int li = (pw * 4 + wcc) * 64 + (t & 31) + hh * 32;
        const float v = WV[li];
        const int ii = WI[li];
        if (v < fbv || (v == fbv && ii < fbi)) { fbv = v; fbi = ii; }
      }
    out[OFF_A + n0 + t] = (float)fbi;
  }
}

// ---------------- gather: emb[d][pix] = W[d][argmin[pix]] -------------------
// runs AFTER k_dist (zq scratch in the OFF_E region is dead by then).
__global__ __launch_bounds__(256) void k_gather(const float* __restrict__ Wc,
                                                float* __restrict__ out) {
  const int n0 = blockIdx.x * 32;
  const int b = n0 >> 10, pixbase = n0 & 1023;
  const int t = threadIdx.x;
  const int pix = t & 31;
  const int kidx = (int)out[OFF_A + n0 + pix];
  for (int d = t >> 5; d < 512; d += 8)
    out[OFF_E + ((size_t)(b * 512 + d)) * 1024 + pixbase + pix] = Wc[(size_t)d * 512 + kidx];
}

// ---------------- decode: conv_transpose (kernel spatially FLIPPED) ---------
__global__ __launch_bounds__(256) void k_decode(const float* __restrict__ dw,
                                                const float* __restrict__ db,
                                                float* out) {
  __shared__ __align__(16) float Qs[32][132];
  __shared__ __align__(16) float Ws3[32][68];
  const int n0 = blockIdx.x * 128;
  const int b = n0 / PIXB, pixbase = n0 % PIXB;
  const int mt = blockIdx.y;
  const int t = threadIdx.x;
  const int pg = t & 31, ck = t >> 5;
  float acc[4][8];
#pragma unroll
  for (int p = 0; p < 4; ++p)
#pragma unroll
    for (int k = 0; k < 8; ++k) acc[p][k] = 0.f;
  for (int dc = 0; dc < 16; ++dc) {
#pragma unroll
    for (int ii = 0; ii < 4; ++ii) {
      const int id = t + ii * 256;
      const int dd = id >> 5, p4 = id & 31;
      *reinterpret_cast<float4*>(&Qs[dd][p4 * 4]) =
        *reinterpret_cast<const float4*>(&out[OFF_E + ((size_t)b * 512 + dc * 32 + dd) * 1024 + pixbase + p4 * 4]);
    }
#pragma unroll
    for (int ii = 0; ii < 2; ++ii) {
      const int id = t + ii * 256;
      const int dd = id >> 4, m4 = id & 15;
      *reinterpret_cast<float4*>(&Ws3[dd][m4 * 4]) =
        *reinterpret_cast<const float4*>(&dw[(size_t)(dc * 32 + dd) * 192 + mt * 64 + m4 * 4]);
    }
    __syncthreads();
#pragma unroll
    for (int dd = 0; dd < 32; ++dd) {
      const float4 qv = *reinterpret_cast<const float4*>(&Qs[dd][pg * 4]);
      const float4 wa = *reinterpret_cast<const float4*>(&Ws3[dd][ck * 8]);
      const float4 wb = *reinterpret_cast<const float4*>(&Ws3[dd][ck * 8 + 4]);
      const float q[4] = {qv.x, qv.y, qv.z, qv.w};
      const float w[8] = {wa.x, wa.y, wa.z, wa.w, wb.x, wb.y, wb.z, wb.w};
#pragma unroll
      for (int p = 0; p < 4; ++p)
#pragma unroll
        for (int k = 0; k < 8; ++k) acc[p][k] = fmaf(q[p], w[k], acc[p][k]);
    }
    __syncthreads();
  }
  const int ckg = mt * 8 + ck;
  const int c = ckg >> 3, ki = ckg & 7;
  const float bias = db[c];
#pragma unroll
  for (int p = 0; p < 4; ++p) {
    const int pix = pixbase + pg * 4 + p;
    const int i = pix >> 5, j = pix & 31;
    const size_t base = (((size_t)b * 3 + c) * 256 + i * 8 + 7 - ki) * 256 + j * 8;
#pragma unroll
    for (int kj = 0; kj < 8; ++kj) out[base + 7 - kj] = acc[p][kj] + bias;
  }
}

extern "C" void kernel_launch(void* const* d_in, const int* in_sizes, int n_in,
                              void* d_out, int out_size, void* d_ws, size_t ws_size,
                              hipStream_t stream) {
  const float* x     = (const float*)d_in[0];
  const float* enc_w = (const float*)d_in[1];
  const float* enc_b = (const float*)d_in[2];
  const float* dec_w = (const float*)d_in[3];
  const float* dec_b = (const float*)d_in[4];
  const float* emb_w = (const float*)d_in[5];
  float* out = (float*)d_out;
  float* w2 = (float*)d_ws;                          // 512 floats
  _Float16* wq  = (_Float16*)d_out;                  // 1MB in recon region (overwritten by k_decode)
  _Float16* zqh = (_Float16*)((char*)d_out + 92274688);  // OFF_E*4: zq splits (67.1MB region fit)

  k_prep<<<dim3(9, 8), 256, 0, stream>>>(emb_w, wq, w2);
  k_encode<<<dim3(512, 8), 256, 0, stream>>>(x, enc_w, enc_b, zqh, out);
  k_dist<<<512, 512, 0, stream>>>(wq, zqh, w2, out);
  k_gather<<<1024, 256, 0, stream>>>(emb_w, out);
  k_decode<<<dim3(256, 3), 256, 0, stream>>>(dec_w, dec_b, out);
}

// Round 8
// 347.180 us; speedup vs baseline: 1.1525x; 1.1314x over previous
//
#include <hip/hip_runtime.h>
#include <cfloat>

#define PIXB 1024
static const size_t OFF_Z = 6291456;   // recon = 32*3*256*256
static const size_t OFF_E = 23068672;  // OFF_Z + 32*512*32*32
static const size_t OFF_A = 39845888;  // OFF_E + 32*512*32*32

typedef __attribute__((address_space(1))) const unsigned int cg_u32;
typedef __attribute__((address_space(3))) unsigned int l_u32;
typedef _Float16 f16x8 __attribute__((ext_vector_type(8)));
typedef _Float16 f16x4 __attribute__((ext_vector_type(4)));
typedef float f32x16 __attribute__((ext_vector_type(16)));

#define SPLIT_SCALE 4096.0f
#define SPLIT_INV   (1.0f / 4096.0f)

// ---------------- prep: W -> pre-swizzled fp16-split chunk images + w2 ------
// Layout (halves): wq[cp*262144 + ch*16384 + s*8192 + c*32 + slot_eff*8 + j]
//   cp = 256-code pass, ch = K-chunk of 32, s = split (h/l), c = code_local,
//   slot_eff = (k>>3) ^ ((c>>1)&3)  [16B-slot XOR swizzle], j = k&7.
// Staged linearly into LDS by k_dist; swizzle makes ds_read_b128 of 32
// consecutive codes bank-conflict-free (column = (4c+slot_eff) mod 8 is
// bijective per 8-lane group). 1MB total, in recon region of d_out.
__global__ __launch_bounds__(256) void k_prep(const float* __restrict__ W,
                                              _Float16* __restrict__ wq,
                                              float* __restrict__ w2) {
  const int t = threadIdx.x;
  const int bx = blockIdx.x;
  if (bx >= 32) {               // w2: 2 blocks
    const int k = (bx - 32) * 256 + t;
    float acc = 0.f;
    for (int d = 0; d < 512; ++d) { const float v = W[(size_t)d * 512 + k]; acc = fmaf(v, v, acc); }
    w2[k] = acc;
    return;
  }
  __shared__ float T[32][260];
  const int cp = bx >> 4, ch = bx & 15;
#pragma unroll
  for (int i = 0; i < 32; ++i)
    T[i][t] = W[(size_t)(ch * 32 + i) * 512 + cp * 256 + t];
  __syncthreads();
#pragma unroll
  for (int j = 0; j < 4; ++j) {
    const int u = j * 256 + t;
    const int c = u >> 2, slot = u & 3;
    const int se = slot ^ ((c >> 1) & 3);
    f16x8 h, l;
#pragma unroll
    for (int jj = 0; jj < 8; ++jj) {
      const float v = T[slot * 8 + jj][c];
      const _Float16 hh = (_Float16)v;
      h[jj] = hh;
      l[jj] = (_Float16)((v - (float)hh) * SPLIT_SCALE);
    }
    _Float16* base = wq + cp * 262144 + ch * 16384 + c * 32 + se * 8;
    *(f16x8*)(base) = h;            // split 0
    *(f16x8*)(base + 8192) = l;     // split 1
  }
}

// ---------------- encode: z_e = conv(x) + b, as GEMM 512x192 @ 192x32768 ----
// also emits zq (fp16 splits, [pix][d] layout) via LDS transpose.
__global__ __launch_bounds__(256) void k_encode(const float* __restrict__ x,
                                                const float* __restrict__ ew,
                                                const float* __restrict__ eb,
                                                _Float16* __restrict__ zqh,
                                                float* __restrict__ out) {
  __shared__ __align__(16) float Ps[16][68];
  __shared__ __align__(16) float Ws[16][68];
  __shared__ __align__(16) _Float16 ZT[64][80];   // 10KB transpose buffer
  const int n0 = blockIdx.x * 64;
  const int b = n0 / PIXB;
  const int pixbase = n0 % PIXB;
  const int i0 = pixbase >> 5;
  const int c0 = blockIdx.y * 64;
  const int t = threadIdx.x;
  const int tx = t & 15, ty = t >> 4;
  float acc[4][4];
#pragma unroll
  for (int m = 0; m < 4; ++m)
#pragma unroll
    for (int p = 0; p < 4; ++p) acc[m][p] = 0.f;

  const int jj = t >> 3, kjj = t & 7;
  for (int kc = 0; kc < 12; ++kc) {
    const int ci = kc >> 2, kip = kc & 3;
#pragma unroll
    for (int rr = 0; rr < 4; ++rr) {
      const int di = rr >> 1, dki = rr & 1;
      const int row = (i0 + di) * 8 + kip * 2 + dki;
      const float v = x[(((size_t)b * 3 + ci) * 256 + row) * 256 + t];
      Ps[dki * 8 + kjj][di * 32 + jj] = v;
    }
    const int k0 = kc * 16;
#pragma unroll
    for (int ii = 0; ii < 4; ++ii) {
      const int idx = t + ii * 256;
      const int cc = idx >> 4, kk = idx & 15;
      Ws[kk][cc] = ew[(size_t)(c0 + cc) * 192 + k0 + kk];
    }
    __syncthreads();
#pragma unroll
    for (int kk = 0; kk < 16; ++kk) {
      const float4 av = *reinterpret_cast<const float4*>(&Ws[kk][ty * 4]);
      const float4 bv = *reinterpret_cast<const float4*>(&Ps[kk][tx * 4]);
      const float a[4] = {av.x, av.y, av.z, av.w};
      const float bb[4] = {bv.x, bv.y, bv.z, bv.w};
#pragma unroll
      for (int m = 0; m < 4; ++m)
#pragma unroll
        for (int p = 0; p < 4; ++p) acc[m][p] = fmaf(a[m], bb[p], acc[m][p]);
    }
    __syncthreads();
  }
  float zf[4][4];
#pragma unroll
  for (int m = 0; m < 4; ++m) {
    const int c = c0 + ty * 4 + m;
    const float bias = eb[c];
#pragma unroll
    for (int p = 0; p < 4; ++p) zf[m][p] = acc[m][p] + bias;
    float4 v;
    v.x = zf[m][0]; v.y = zf[m][1]; v.z = zf[m][2]; v.w = zf[m][3];
    *reinterpret_cast<float4*>(&out[OFF_Z + ((size_t)b * 512 + c) * 1024 + pixbase + tx * 4]) = v;
  }
  // ---- zq emission: two passes (h, l) through LDS transpose ----
#pragma unroll
  for (int s = 0; s < 2; ++s) {
    __syncthreads();
#pragma unroll
    for (int p = 0; p < 4; ++p) {
      f16x4 v;
#pragma unroll
      for (int m = 0; m < 4; ++m) {
        const float f = zf[m][p];
        const _Float16 h = (_Float16)f;
        v[m] = (s == 0) ? h : (_Float16)((f - (float)h) * SPLIT_SCALE);
      }
      *(f16x4*)&ZT[tx * 4 + p][ty * 4] = v;
    }
    __syncthreads();
    _Float16* dst = zqh + (size_t)s * 16777216 +
                    ((size_t)(b * 1024) + pixbase + (t >> 2)) * 512 + c0;
#pragma unroll
    for (int g = 0; g < 2; ++g) {
      const int seg = (t & 3) + g * 4;
      *(f16x8*)(dst + seg * 8) = *(const f16x8*)&ZT[t >> 2][seg * 8];
    }
  }
}

// -------- distance + argmin: 2-phase LDS-pipelined MFMA GEMM ---------------
// Block 512 thr = 8 waves (wc = w&3 code slice of 64, wp = w>>2 pixel half of
// 32). Two 256-code passes so acc = 64 AGPR and total regs fit 4 waves/SIMD
// (round 7: reg-direct streaming could not hide L2 latency - MfmaUtil 12%).
// W staged chunk-by-chunk via global_load_lds into a 2x32KB double buffer
// (pre-swizzled by k_prep -> linear stage, conflict-free swizzled ds_read).
// One __syncthreads per chunk; stage of chunk ch+1 issued BEFORE compute of
// chunk ch (T3 minimum 2-phase). z (B operand) global->reg, 4 loads/chunk.
// Per-accumulator MFMA sequence bit-identical to rounds 5-7 (all passed).
__global__ __launch_bounds__(512) void k_dist(const _Float16* __restrict__ wq,
                                              const _Float16* __restrict__ zq,
                                              const float* __restrict__ w2ws,
                                              float* __restrict__ out) {
  __shared__ __align__(16) _Float16 WLDS[32768];   // 2 x 32KB double buffer
  __shared__ float w2L[512];
  __shared__ float WV[512];
  __shared__ int   WI[512];
  const int t = threadIdx.x;
  w2L[t] = w2ws[t];
  const int w = t >> 6, lane = t & 63;
  const int wc = w & 3, wp = w >> 2;
  const int n0 = blockIdx.x * 64;
  const int b = n0 >> 10, pixbase = n0 & 1023;
  const int row = lane & 31;
  const int kl16 = (lane >> 5) << 4;   // byte offset of this lane's k-group

  // A-read base byte offsets within a 32KB buffer (per ct, ks), swizzled
  int abase[2][2];
#pragma unroll
  for (int ct = 0; ct < 2; ++ct) {
    const int cl = wc * 64 + ct * 32 + row;
    const int sw = ((cl >> 1) & 3) << 4;
#pragma unroll
    for (int ks = 0; ks < 2; ++ks)
      abase[ct][ks] = cl * 64 + (((ks << 5) | kl16) ^ sw);
  }
  const char* LB = (const char*)WLDS;

  const _Float16* zh = zq + ((size_t)(b * 1024) + pixbase + wp * 32 + row) * 512 + ((lane >> 5) << 3);
  const _Float16* zl = zh + 16777216;

  float bv = FLT_MAX; int bi = 0x7fffffff;

#pragma unroll
  for (int cp = 0; cp < 2; ++cp) {
    const _Float16* wbase = wq + cp * 262144;
    f32x16 accA[2], accB[2];
#pragma unroll
    for (int ct = 0; ct < 2; ++ct) { accA[ct] = (f32x16)(0.0f); accB[ct] = (f32x16)(0.0f); }
    // prologue: stage chunk 0 -> parity 0
    {
      const _Float16* src = wbase + t * 8;
#pragma unroll
      for (int i = 0; i < 4; ++i)
        __builtin_amdgcn_global_load_lds((cg_u32*)(src + i * 4096),
            (l_u32*)((char*)WLDS + i * 8192 + t * 16), 16, 0, 0);
    }
    __syncthreads();
#pragma unroll
    for (int ch = 0; ch < 16; ++ch) {
      const int parity = ch & 1;
      if (ch < 15) {                 // stage next chunk into other buffer
        const _Float16* src = wbase + (ch + 1) * 16384 + t * 8;
        const int pd = (ch + 1) & 1;
#pragma unroll
        for (int i = 0; i < 4; ++i)
          __builtin_amdgcn_global_load_lds((cg_u32*)(src + i * 4096),
              (l_u32*)((char*)WLDS + pd * 32768 + i * 8192 + t * 16), 16, 0, 0);
      }
      f16x8 Bh[2], Bl[2];
#pragma unroll
      for (int ks = 0; ks < 2; ++ks) {
        Bh[ks] = *(const f16x8*)(zh + ch * 32 + ks * 16);
        Bl[ks] = *(const f16x8*)(zl + ch * 32 + ks * 16);
      }
#pragma unroll
      for (int ct = 0; ct < 2; ++ct) {
#pragma unroll
        for (int ks = 0; ks < 2; ++ks) {
          const f16x8 Ah = *(const f16x8*)(LB + parity * 32768 + abase[ct][ks]);
          const f16x8 Al = *(const f16x8*)(LB + parity * 32768 + 16384 + abase[ct][ks]);
          accA[ct] = __builtin_amdgcn_mfma_f32_32x32x16_f16(Ah, Bh[ks], accA[ct], 0, 0, 0);
          accB[ct] = __builtin_amdgcn_mfma_f32_32x32x16_f16(Ah, Bl[ks], accB[ct], 0, 0, 0);
          accB[ct] = __builtin_amdgcn_mfma_f32_32x32x16_f16(Al, Bh[ks], accB[ct], 0, 0, 0);
        }
      }
      __syncthreads();
    }
    // ---- per-pass d2 + argmin update (registers only) ----
    // C/D: col = lane&31 (pixel), row = (r&3)+8*(r>>2)+4*(lane>>5)
#pragma unroll
    for (int ct = 0; ct < 2; ++ct) {
#pragma unroll
      for (int r = 0; r < 16; ++r) {
        const int code = cp * 256 + wc * 64 + ct * 32 +
                         ((r & 3) + ((r >> 2) << 3) + ((lane >> 5) << 2));
        const float zw = fmaf(accB[ct][r], SPLIT_INV, accA[ct][r]);
        const float d2 = fmaf(-2.f, zw, w2L[code]);
        if (d2 < bv || (d2 == bv && code < bi)) { bv = d2; bi = code; }
      }
    }
  }

  WV[w * 64 + lane] = bv;
  WI[w * 64 + lane] = bi;
  __syncthreads();
  // ---- final per-pixel reduce (8 candidates), write argmin ----
  if (t < 64) {
    const int pw = t >> 5;
    float fbv = FLT_MAX; int fbi = 0x7fffffff;
#pragma unroll
    for (int wcc = 0; wcc < 4; ++wcc)
#pragma unroll
      for (int hh = 0; hh < 2; ++hh) {
        const int li = (pw * 4 + wcc) * 64 + (t & 31) + hh * 32;
        const float v = WV[li];
        const int ii = WI[li];
        if (v < fbv || (v == fbv && ii < fbi)) { fbv = v; fbi = ii; }
      }
    out[OFF_A + n0 + t] = (float)fbi;
  }
}

// ---------------- gather: emb[d][pix] = W[d][argmin[pix]] -------------------
__global__ __launch_bounds__(256) void k_gather(const float* __restrict__ Wc,
                                                float* __restrict__ out) {
  const int n0 = blockIdx.x * 32;
  const int b = n0 >> 10, pixbase = n0 & 1023;
  const int t = threadIdx.x;
  const int pix = t & 31;
  const int kidx = (int)out[OFF_A + n0 + pix];
  for (int d = t >> 5; d < 512; d += 8)
    out[OFF_E + ((size_t)(b * 512 + d)) * 1024 + pixbase + pix] = Wc[(size_t)d * 512 + kidx];
}

// ---------------- decode: conv_transpose (kernel spatially FLIPPED) ---------
__global__ __launch_bounds__(256) void k_decode(const float* __restrict__ dw,
                                                const float* __restrict__ db,
                                                float* out) {
  __shared__ __align__(16) float Qs[32][132];
  __shared__ __align__(16) float Ws3[32][68];
  const int n0 = blockIdx.x * 128;
  const int b = n0 / PIXB, pixbase = n0 % PIXB;
  const int mt = blockIdx.y;
  const int t = threadIdx.x;
  const int pg = t & 31, ck = t >> 5;
  float acc[4][8];
#pragma unroll
  for (int p = 0; p < 4; ++p)
#pragma unroll
    for (int k = 0; k < 8; ++k) acc[p][k] = 0.f;
  for (int dc = 0; dc < 16; ++dc) {
#pragma unroll
    for (int ii = 0; ii < 4; ++ii) {
      const int id = t + ii * 256;
      const int dd = id >> 5, p4 = id & 31;
      *reinterpret_cast<float4*>(&Qs[dd][p4 * 4]) =
        *reinterpret_cast<const float4*>(&out[OFF_E + ((size_t)b * 512 + dc * 32 + dd) * 1024 + pixbase + p4 * 4]);
    }
#pragma unroll
    for (int ii = 0; ii < 2; ++ii) {
      const int id = t + ii * 256;
      const int dd = id >> 4, m4 = id & 15;
      *reinterpret_cast<float4*>(&Ws3[dd][m4 * 4]) =
        *reinterpret_cast<const float4*>(&dw[(size_t)(dc * 32 + dd) * 192 + mt * 64 + m4 * 4]);
    }
    __syncthreads();
#pragma unroll
    for (int dd = 0; dd < 32; ++dd) {
      const float4 qv = *reinterpret_cast<const float4*>(&Qs[dd][pg * 4]);
      const float4 wa = *reinterpret_cast<const float4*>(&Ws3[dd][ck * 8]);
      const float4 wb = *reinterpret_cast<const float4*>(&Ws3[dd][ck * 8 + 4]);
      const float q[4] = {qv.x, qv.y, qv.z, qv.w};
      const float w[8] = {wa.x, wa.y, wa.z, wa.w, wb.x, wb.y, wb.z, wb.w};
#pragma unroll
      for (int p = 0; p < 4; ++p)
#pragma unroll
        for (int k = 0; k < 8; ++k) acc[p][k] = fmaf(q[p], w[k], acc[p][k]);
    }
    __syncthreads();
  }
  const int ckg = mt * 8 + ck;
  const int c = ckg >> 3, ki = ckg & 7;
  const float bias = db[c];
#pragma unroll
  for (int p = 0; p < 4; ++p) {
    const int pix = pixbase + pg * 4 + p;
    const int i = pix >> 5, j = pix & 31;
    const size_t base = (((size_t)b * 3 + c) * 256 + i * 8 + 7 - ki) * 256 + j * 8;
#pragma unroll
    for (int kj = 0; kj < 8; ++kj) out[base + 7 - kj] = acc[p][kj] + bias;
  }
}

extern "C" void kernel_launch(void* const* d_in, const int* in_sizes, int n_in,
                              void* d_out, int out_size, void* d_ws, size_t ws_size,
                              hipStream_t stream) {
  const float* x     = (const float*)d_in[0];
  const float* enc_w = (const float*)d_in[1];
  const float* enc_b = (const float*)d_in[2];
  const float* dec_w = (const float*)d_in[3];
  const float* dec_b = (const float*)d_in[4];
  const float* emb_w = (const float*)d_in[5];
  float* out = (float*)d_out;
  float* w2 = (float*)d_ws;                          // 512 floats
  _Float16* wq  = (_Float16*)d_out;                  // 1MB in recon region (overwritten by k_decode)
  _Float16* zqh = (_Float16*)((char*)d_out + 92274688);  // OFF_E*4: zq splits (67.1MB region fit)

  k_prep<<<34, 256, 0, stream>>>(emb_w, wq, w2);
  k_encode<<<dim3(512, 8), 256, 0, stream>>>(x, enc_w, enc_b, zqh, out);
  k_dist<<<512, 512, 0, stream>>>(wq, zqh, w2, out);
  k_gather<<<1024, 256, 0, stream>>>(emb_w, out);
  k_decode<<<dim3(256, 3), 256, 0, stream>>>(dec_w, dec_b, out);
}

// Round 9
// 289.974 us; speedup vs baseline: 1.3798x; 1.1973x over previous
//
#include <hip/hip_runtime.h>
#include <cfloat>

#define PIXB 1024
static const size_t OFF_Z = 6291456;   // recon = 32*3*256*256
static const size_t OFF_E = 23068672;  // OFF_Z + 32*512*32*32
static const size_t OFF_A = 39845888;  // OFF_E + 32*512*32*32

typedef __attribute__((address_space(1))) const unsigned int cg_u32;
typedef __attribute__((address_space(3))) unsigned int l_u32;
typedef _Float16 f16x8 __attribute__((ext_vector_type(8)));
typedef _Float16 f16x4 __attribute__((ext_vector_type(4)));
typedef float f32x16 __attribute__((ext_vector_type(16)));

#define SPLIT_SCALE 4096.0f
#define SPLIT_INV   (1.0f / 4096.0f)

// ---------------- prep: all weight-side tables ------------------------------
// bx 0..31 : wq chunk-images (k_dist A operand, swizzled; recon region, 1MB)
// bx 32..33: w2 (d_ws)
// bx 34..97: wrow [code][d] fp16 (decode gather table, d_ws) [do_aux]
// bx 98..109: dwh [m=192][d] fp16 (decode A operand, d_ws)   [do_aux]
__global__ __launch_bounds__(256) void k_prep(const float* __restrict__ W,
                                              const float* __restrict__ dw,
                                              _Float16* __restrict__ wq,
                                              float* __restrict__ w2,
                                              _Float16* __restrict__ wrow,
                                              _Float16* __restrict__ dwh,
                                              int do_aux) {
  const int t = threadIdx.x;
  const int bx = blockIdx.x;
  __shared__ float T[64][65];
  __shared__ float T2[128][65];
  if (bx < 32) {
    __shared__ float TS[32][260];
    const int cp = bx >> 4, ch = bx & 15;
#pragma unroll
    for (int i = 0; i < 32; ++i)
      TS[i][t] = W[(size_t)(ch * 32 + i) * 512 + cp * 256 + t];
    __syncthreads();
#pragma unroll
    for (int j = 0; j < 4; ++j) {
      const int u = j * 256 + t;
      const int c = u >> 2, slot = u & 3;
      const int se = slot ^ ((c >> 1) & 3);
      f16x8 h, l;
#pragma unroll
      for (int jj = 0; jj < 8; ++jj) {
        const float v = TS[slot * 8 + jj][c];
        const _Float16 hh = (_Float16)v;
        h[jj] = hh;
        l[jj] = (_Float16)((v - (float)hh) * SPLIT_SCALE);
      }
      _Float16* base = wq + cp * 262144 + ch * 16384 + c * 32 + se * 8;
      *(f16x8*)(base) = h;
      *(f16x8*)(base + 8192) = l;
    }
    return;
  }
  if (bx < 34) {
    const int k = (bx - 32) * 256 + t;
    float acc = 0.f;
    for (int d = 0; d < 512; ++d) { const float v = W[(size_t)d * 512 + k]; acc = fmaf(v, v, acc); }
    w2[k] = acc;
    return;
  }
  if (!do_aux) return;
  if (bx < 98) {                 // wrow: transpose W [d][c] -> fp16 [c][d]
    const int id = bx - 34;
    const int c0 = (id & 7) * 64, d0 = (id >> 3) * 64;
#pragma unroll
    for (int i = 0; i < 16; ++i) {
      const int dl = i * 4 + (t >> 6);
      T[dl][t & 63] = W[(size_t)(d0 + dl) * 512 + c0 + (t & 63)];
    }
    __syncthreads();
#pragma unroll
    for (int i = 0; i < 16; ++i) {
      const int cl = i * 4 + (t >> 6);
      const int dl = t & 63;
      wrow[(size_t)(c0 + cl) * 512 + d0 + dl] = (_Float16)T[dl][cl];
    }
    return;
  }
  {                              // dwh: transpose dec_w [d][m] -> fp16 [m][d]
    const int id = bx - 98;
    const int m0 = (id % 3) * 64, d0 = (id / 3) * 128;
#pragma unroll
    for (int i = 0; i < 32; ++i) {
      const int idx = i * 256 + t;
      const int dl = idx >> 6, ml = idx & 63;
      T2[dl][ml] = dw[(size_t)(d0 + dl) * 192 + m0 + ml];
    }
    __syncthreads();
#pragma unroll
    for (int i = 0; i < 32; ++i) {
      const int idx = i * 256 + t;
      const int ml = idx >> 7, dl = idx & 127;
      dwh[(size_t)(m0 + ml) * 512 + d0 + dl] = (_Float16)T2[dl][ml];
    }
  }
}

// ---------------- encode: z_e = conv(x) + b, as GEMM 512x192 @ 192x32768 ----
// also emits zq (fp16 splits, [pix][d] layout) via LDS transpose.
__global__ __launch_bounds__(256) void k_encode(const float* __restrict__ x,
                                                const float* __restrict__ ew,
                                                const float* __restrict__ eb,
                                                _Float16* __restrict__ zqh,
                                                float* __restrict__ out) {
  __shared__ __align__(16) float Ps[16][68];
  __shared__ __align__(16) float Ws[16][68];
  __shared__ __align__(16) _Float16 ZT[64][80];
  const int n0 = blockIdx.x * 64;
  const int b = n0 / PIXB;
  const int pixbase = n0 % PIXB;
  const int i0 = pixbase >> 5;
  const int c0 = blockIdx.y * 64;
  const int t = threadIdx.x;
  const int tx = t & 15, ty = t >> 4;
  float acc[4][4];
#pragma unroll
  for (int m = 0; m < 4; ++m)
#pragma unroll
    for (int p = 0; p < 4; ++p) acc[m][p] = 0.f;

  const int jj = t >> 3, kjj = t & 7;
  for (int kc = 0; kc < 12; ++kc) {
    const int ci = kc >> 2, kip = kc & 3;
#pragma unroll
    for (int rr = 0; rr < 4; ++rr) {
      const int di = rr >> 1, dki = rr & 1;
      const int row = (i0 + di) * 8 + kip * 2 + dki;
      const float v = x[(((size_t)b * 3 + ci) * 256 + row) * 256 + t];
      Ps[dki * 8 + kjj][di * 32 + jj] = v;
    }
    const int k0 = kc * 16;
#pragma unroll
    for (int ii = 0; ii < 4; ++ii) {
      const int idx = t + ii * 256;
      const int cc = idx >> 4, kk = idx & 15;
      Ws[kk][cc] = ew[(size_t)(c0 + cc) * 192 + k0 + kk];
    }
    __syncthreads();
#pragma unroll
    for (int kk = 0; kk < 16; ++kk) {
      const float4 av = *reinterpret_cast<const float4*>(&Ws[kk][ty * 4]);
      const float4 bv = *reinterpret_cast<const float4*>(&Ps[kk][tx * 4]);
      const float a[4] = {av.x, av.y, av.z, av.w};
      const float bb[4] = {bv.x, bv.y, bv.z, bv.w};
#pragma unroll
      for (int m = 0; m < 4; ++m)
#pragma unroll
        for (int p = 0; p < 4; ++p) acc[m][p] = fmaf(a[m], bb[p], acc[m][p]);
    }
    __syncthreads();
  }
  float zf[4][4];
#pragma unroll
  for (int m = 0; m < 4; ++m) {
    const int c = c0 + ty * 4 + m;
    const float bias = eb[c];
#pragma unroll
    for (int p = 0; p < 4; ++p) zf[m][p] = acc[m][p] + bias;
    float4 v;
    v.x = zf[m][0]; v.y = zf[m][1]; v.z = zf[m][2]; v.w = zf[m][3];
    *reinterpret_cast<float4*>(&out[OFF_Z + ((size_t)b * 512 + c) * 1024 + pixbase + tx * 4]) = v;
  }
#pragma unroll
  for (int s = 0; s < 2; ++s) {
    __syncthreads();
#pragma unroll
    for (int p = 0; p < 4; ++p) {
      f16x4 v;
#pragma unroll
      for (int m = 0; m < 4; ++m) {
        const float f = zf[m][p];
        const _Float16 h = (_Float16)f;
        v[m] = (s == 0) ? h : (_Float16)((f - (float)h) * SPLIT_SCALE);
      }
      *(f16x4*)&ZT[tx * 4 + p][ty * 4] = v;
    }
    __syncthreads();
    _Float16* dst = zqh + (size_t)s * 16777216 +
                    ((size_t)(b * 1024) + pixbase + (t >> 2)) * 512 + c0;
#pragma unroll
    for (int g = 0; g < 2; ++g) {
      const int seg = (t & 3) + g * 4;
      *(f16x8*)(dst + seg * 8) = *(const f16x8*)&ZT[t >> 2][seg * 8];
    }
  }
}

// -------- distance + argmin: LDS-pipelined W + 2-ahead z reg prefetch -------
// Round 8 showed MfmaUtil 18% = pure z-latency stall (z consumed same chunk
// it was issued; HBM ~900cy). Now z(ch+2) is register-prefetched while chunk
// ch computes (~770cy coverage). Reg loads are NOT drained by the per-chunk
// barrier (only global_load_lds is), so the prefetch survives. MFMA sequence
// per accumulator is bit-identical to rounds 5-8 (all passed).
__global__ __launch_bounds__(512) void k_dist(const _Float16* __restrict__ wq,
                                              const _Float16* __restrict__ zq,
                                              const float* __restrict__ w2ws,
                                              float* __restrict__ out) {
  __shared__ __align__(16) _Float16 WLDS[32768];   // 2 x 32KB double buffer
  __shared__ float w2L[512];
  __shared__ float WV[512];
  __shared__ int   WI[512];
  const int t = threadIdx.x;
  w2L[t] = w2ws[t];
  const int w = t >> 6, lane = t & 63;
  const int wc = w & 3, wp = w >> 2;
  const int n0 = blockIdx.x * 64;
  const int b = n0 >> 10, pixbase = n0 & 1023;
  const int row = lane & 31;
  const int kl16 = (lane >> 5) << 4;

  int abase[2][2];
#pragma unroll
  for (int ct = 0; ct < 2; ++ct) {
    const int cl = wc * 64 + ct * 32 + row;
    const int sw = ((cl >> 1) & 3) << 4;
#pragma unroll
    for (int ks = 0; ks < 2; ++ks)
      abase[ct][ks] = cl * 64 + (((ks << 5) | kl16) ^ sw);
  }
  const char* LB = (const char*)WLDS;

  const _Float16* zh = zq + ((size_t)(b * 1024) + pixbase + wp * 32 + row) * 512 + ((lane >> 5) << 3);
  const _Float16* zl = zh + 16777216;

  float bv = FLT_MAX; int bi = 0x7fffffff;

#pragma unroll
  for (int cp = 0; cp < 2; ++cp) {
    const _Float16* wbase = wq + cp * 262144;
    f32x16 accA[2], accB[2];
#pragma unroll
    for (int ct = 0; ct < 2; ++ct) { accA[ct] = (f32x16)(0.0f); accB[ct] = (f32x16)(0.0f); }
    f16x8 B[3][4];   // z ring buffer: [slot][{h0,h1,l0,l1}], static via unroll
    // prologue: stage W chunk 0; preload z chunks 0,1
    {
      const _Float16* src = wbase + t * 8;
#pragma unroll
      for (int i = 0; i < 4; ++i)
        __builtin_amdgcn_global_load_lds((cg_u32*)(src + i * 4096),
            (l_u32*)((char*)WLDS + i * 8192 + t * 16), 16, 0, 0);
    }
#pragma unroll
    for (int pc = 0; pc < 2; ++pc) {
      B[pc][0] = *(const f16x8*)(zh + pc * 32);
      B[pc][1] = *(const f16x8*)(zh + pc * 32 + 16);
      B[pc][2] = *(const f16x8*)(zl + pc * 32);
      B[pc][3] = *(const f16x8*)(zl + pc * 32 + 16);
    }
    __syncthreads();
#pragma unroll
    for (int ch = 0; ch < 16; ++ch) {
      const int parity = ch & 1;
      if (ch < 15) {                 // stage next W chunk into other buffer
        const _Float16* src = wbase + (ch + 1) * 16384 + t * 8;
#pragma unroll
        for (int i = 0; i < 4; ++i)
          __builtin_amdgcn_global_load_lds((cg_u32*)(src + i * 4096),
              (l_u32*)((char*)WLDS + (parity ^ 1) * 32768 + i * 8192 + t * 16), 16, 0, 0);
      }
      if (ch < 14) {                 // prefetch z two chunks ahead
        const int s = (ch + 2) % 3;
        B[s][0] = *(const f16x8*)(zh + (ch + 2) * 32);
        B[s][1] = *(const f16x8*)(zh + (ch + 2) * 32 + 16);
        B[s][2] = *(const f16x8*)(zl + (ch + 2) * 32);
        B[s][3] = *(const f16x8*)(zl + (ch + 2) * 32 + 16);
      }
      const int cs = ch % 3;
#pragma unroll
      for (int ct = 0; ct < 2; ++ct) {
#pragma unroll
        for (int ks = 0; ks < 2; ++ks) {
          const f16x8 Ah = *(const f16x8*)(LB + parity * 32768 + abase[ct][ks]);
          const f16x8 Al = *(const f16x8*)(LB + parity * 32768 + 16384 + abase[ct][ks]);
          accA[ct] = __builtin_amdgcn_mfma_f32_32x32x16_f16(Ah, B[cs][ks], accA[ct], 0, 0, 0);
          accB[ct] = __builtin_amdgcn_mfma_f32_32x32x16_f16(Ah, B[cs][2 + ks], accB[ct], 0, 0, 0);
          accB[ct] = __builtin_amdgcn_mfma_f32_32x32x16_f16(Al, B[cs][ks], accB[ct], 0, 0, 0);
        }
      }
      __syncthreads();
    }
    // ---- per-pass d2 + argmin update ----
#pragma unroll
    for (int ct = 0; ct < 2; ++ct) {
#pragma unroll
      for (int r = 0; r < 16; ++r) {
        const int code = cp * 256 + wc * 64 + ct * 32 +
                         ((r & 3) + ((r >> 2) << 3) + ((lane >> 5) << 2));
        const float zw = fmaf(accB[ct][r], SPLIT_INV, accA[ct][r]);
        const float d2 = fmaf(-2.f, zw, w2L[code]);
        if (d2 < bv || (d2 == bv && code < bi)) { bv = d2; bi = code; }
      }
    }
  }

  WV[w * 64 + lane] = bv;
  WI[w * 64 + lane] = bi;
  __syncthreads();
  if (t < 64) {
    const int pw = t >> 5;
    float fbv = FLT_MAX; int fbi = 0x7fffffff;
#pragma unroll
    for (int wcc = 0; wcc < 4; ++wcc)
#pragma unroll
      for (int hh = 0; hh < 2; ++hh) {
        const int li = (pw * 4 + wcc) * 64 + (t & 31) + hh * 32;
        const float v = WV[li];
        const int ii = WI[li];
        if (v < fbv || (v == fbv && ii < fbi)) { fbv = v; fbi = ii; }
      }
    out[OFF_A + n0 + t] = (float)fbi;
  }
}

// ---------------- gather: emb[d][pix] = W[d][argmin[pix]] -------------------
__global__ __launch_bounds__(256) void k_gather(const float* __restrict__ Wc,
                                                float* __restrict__ out) {
  const int n0 = blockIdx.x * 32;
  const int b = n0 >> 10, pixbase = n0 & 1023;
  const int t = threadIdx.x;
  const int pix = t & 31;
  const int kidx = (int)out[OFF_A + n0 + pix];
  for (int d = t >> 5; d < 512; d += 8)
    out[OFF_E + ((size_t)(b * 512 + d)) * 1024 + pixbase + pix] = Wc[(size_t)d * 512 + kidx];
}

// -------- decode via single-fp16 MFMA (q in (-0.04,0.04), err ~2e-5) --------
// Block: 128 pix x 192 m, 8 waves (pt = w&3 pixel tile, mg = w>>2 -> 3 m-tiles).
// Per K-chunk(32): q gathered from wrow[kidx][d] (L2) -> reg (issued 2 chunks
// early) -> swizzled LDS (written 1 chunk early); A (dwh, L2-hot) reg-prefetch
// 1 ahead. 6 MFMA/wave/chunk. Epilogue: scatter with conv_transpose flip.
__global__ __launch_bounds__(512) void k_decmfma(const _Float16* __restrict__ wrow,
                                                 const _Float16* __restrict__ dwh,
                                                 const float* __restrict__ db,
                                                 float* __restrict__ out) {
  __shared__ __align__(16) _Float16 QB[2][4096];   // 2 x 8KB (128 pix x 32 d)
  __shared__ int KIDX[128];
  const int t = threadIdx.x;
  const int w = t >> 6, lane = t & 63;
  const int pt = w & 3, mg = w >> 2;
  const int blk = blockIdx.x;
  const int b = blk >> 3;
  const int pixbase = (blk & 7) * 128;
  if (t < 128) KIDX[t] = (int)out[OFF_A + b * 1024 + pixbase + t];
  __syncthreads();
  const int pixS = t >> 2, slotS = t & 3;
  const _Float16* qsrc = wrow + (size_t)KIDX[pixS] * 512 + slotS * 8;
  const int ldsW = pixS * 32 + (slotS ^ ((pixS >> 1) & 3)) * 8;

  const _Float16* ab[3];
#pragma unroll
  for (int mt = 0; mt < 3; ++mt)
    ab[mt] = dwh + (size_t)((mg * 3 + mt) * 32 + (lane & 31)) * 512 + ((lane >> 5) << 3);

  const int brow = pt * 32 + (lane & 31);
  const int bsw = (brow >> 1) & 3;
  int boff[2];
#pragma unroll
  for (int ks = 0; ks < 2; ++ks)
    boff[ks] = brow * 32 + (((ks * 2 + (lane >> 5)) ^ bsw)) * 8;

  f32x16 acc[3];
#pragma unroll
  for (int mt = 0; mt < 3; ++mt) acc[mt] = (f32x16)(0.0f);
  f16x8 A[2][3][2];
  f16x8 qd[2];

  // prologue: q(0) -> QB[0]; A(0) -> regs; issue q(1)
  qd[0] = *(const f16x8*)(qsrc);
#pragma unroll
  for (int mt = 0; mt < 3; ++mt)
#pragma unroll
    for (int ks = 0; ks < 2; ++ks)
      A[0][mt][ks] = *(const f16x8*)(ab[mt] + ks * 16);
  *(f16x8*)&QB[0][ldsW] = qd[0];
  qd[1] = *(const f16x8*)(qsrc + 32);
  __syncthreads();

#pragma unroll
  for (int ch = 0; ch < 16; ++ch) {
    const int par = ch & 1;
    if (ch < 15) {
      *(f16x8*)&QB[par ^ 1][ldsW] = qd[(ch + 1) & 1];   // data arrived (issued ch-1)
#pragma unroll
      for (int mt = 0; mt < 3; ++mt)
#pragma unroll
        for (int ks = 0; ks < 2; ++ks)
          A[par ^ 1][mt][ks] = *(const f16x8*)(ab[mt] + (ch + 1) * 32 + ks * 16);
    }
    if (ch < 14) qd[ch & 1] = *(const f16x8*)(qsrc + (ch + 2) * 32);
    const f16x8 B0 = *(const f16x8*)&QB[par][boff[0]];
    const f16x8 B1 = *(const f16x8*)&QB[par][boff[1]];
#pragma unroll
    for (int mt = 0; mt < 3; ++mt) {
      acc[mt] = __builtin_amdgcn_mfma_f32_32x32x16_f16(A[par][mt][0], B0, acc[mt], 0, 0, 0);
      acc[mt] = __builtin_amdgcn_mfma_f32_32x32x16_f16(A[par][mt][1], B1, acc[mt], 0, 0, 0);
    }
    __syncthreads();
  }

  // epilogue: scatter with flip; C/D col = lane&31 (pix), row per rowfn
  const float b0 = db[0], b1 = db[1], b2 = db[2];
  const int pix = pixbase + pt * 32 + (lane & 31);
  const int i = pix >> 5, j = pix & 31;
#pragma unroll
  for (int mt = 0; mt < 3; ++mt) {
    const int m0 = (mg * 3 + mt) * 32;
#pragma unroll
    for (int r = 0; r < 16; ++r) {
      const int m = m0 + (r & 3) + ((r >> 2) << 3) + ((lane >> 5) << 2);
      const int c = m >> 6, ki = (m >> 3) & 7, kj = m & 7;
      const float bias = (c == 0) ? b0 : ((c == 1) ? b1 : b2);
      out[(((size_t)b * 3 + c) * 256 + i * 8 + 7 - ki) * 256 + j * 8 + 7 - kj] = acc[mt][r] + bias;
    }
  }
}

// ---------------- decode fallback: fp32 VALU (if ws too small) --------------
__global__ __launch_bounds__(256) void k_decode(const float* __restrict__ dw,
                                                const float* __restrict__ db,
                                                float* out) {
  __shared__ __align__(16) float Qs[32][132];
  __shared__ __align__(16) float Ws3[32][68];
  const int n0 = blockIdx.x * 128;
  const int b = n0 / PIXB, pixbase = n0 % PIXB;
  const int mt = blockIdx.y;
  const int t = threadIdx.x;
  const int pg = t & 31, ck = t >> 5;
  float acc[4][8];
#pragma unroll
  for (int p = 0; p < 4; ++p)
#pragma unroll
    for (int k = 0; k < 8; ++k) acc[p][k] = 0.f;
  for (int dc = 0; dc < 16; ++dc) {
#pragma unroll
    for (int ii = 0; ii < 4; ++ii) {
      const int id = t + ii * 256;
      const int dd = id >> 5, p4 = id & 31;
      *reinterpret_cast<float4*>(&Qs[dd][p4 * 4]) =
        *reinterpret_cast<const float4*>(&out[OFF_E + ((size_t)b * 512 + dc * 32 + dd) * 1024 + pixbase + p4 * 4]);
    }
#pragma unroll
    for (int ii = 0; ii < 2; ++ii) {
      const int id = t + ii * 256;
      const int dd = id >> 4, m4 = id & 15;
      *reinterpret_cast<float4*>(&Ws3[dd][m4 * 4]) =
        *reinterpret_cast<const float4*>(&dw[(size_t)(dc * 32 + dd) * 192 + mt * 64 + m4 * 4]);
    }
    __syncthreads();
#pragma unroll
    for (int dd = 0; dd < 32; ++dd) {
      const float4 qv = *reinterpret_cast<const float4*>(&Qs[dd][pg * 4]);
      const float4 wa = *reinterpret_cast<const float4*>(&Ws3[dd][ck * 8]);
      const float4 wb = *reinterpret_cast<const float4*>(&Ws3[dd][ck * 8 + 4]);
      const float q[4] = {qv.x, qv.y, qv.z, qv.w};
      const float wv[8] = {wa.x, wa.y, wa.z, wa.w, wb.x, wb.y, wb.z, wb.w};
#pragma unroll
      for (int p = 0; p < 4; ++p)
#pragma unroll
        for (int k = 0; k < 8; ++k) acc[p][k] = fmaf(q[p], wv[k], acc[p][k]);
    }
    __syncthreads();
  }
  const int ckg = mt * 8 + ck;
  const int c = ckg >> 3, ki = ckg & 7;
  const float bias = db[c];
#pragma unroll
  for (int p = 0; p < 4; ++p) {
    const int pix = pixbase + pg * 4 + p;
    const int i = pix >> 5, j = pix & 31;
    const size_t base = (((size_t)b * 3 + c) * 256 + i * 8 + 7 - ki) * 256 + j * 8;
#pragma unroll
    for (int kj = 0; kj < 8; ++kj) out[base + 7 - kj] = acc[p][kj] + bias;
  }
}

extern "C" void kernel_launch(void* const* d_in, const int* in_sizes, int n_in,
                              void* d_out, int out_size, void* d_ws, size_t ws_size,
                              hipStream_t stream) {
  const float* x     = (const float*)d_in[0];
  const float* enc_w = (const float*)d_in[1];
  const float* enc_b = (const float*)d_in[2];
  const float* dec_w = (const float*)d_in[3];
  const float* dec_b = (const float*)d_in[4];
  const float* emb_w = (const float*)d_in[5];
  float* out = (float*)d_out;
  float* w2 = (float*)d_ws;                              // 2KB
  _Float16* wrow = (_Float16*)((char*)d_ws + 2048);      // 512KB
  _Float16* dwh  = (_Float16*)((char*)d_ws + 2048 + 524288);  // 192KB
  const int do_aux = (ws_size >= (size_t)(2048 + 524288 + 196608)) ? 1 : 0;
  _Float16* wq  = (_Float16*)d_out;                      // 1MB in recon region
  _Float16* zqh = (_Float16*)((char*)d_out + 92274688);  // zq splits in emb region

  k_prep<<<110, 256, 0, stream>>>(emb_w, dec_w, wq, w2, wrow, dwh, do_aux);
  k_encode<<<dim3(512, 8), 256, 0, stream>>>(x, enc_w, enc_b, zqh, out);
  k_dist<<<512, 512, 0, stream>>>(wq, zqh, w2, out);
  k_gather<<<1024, 256, 0, stream>>>(emb_w, out);
  if (do_aux)
    k_decmfma<<<256, 512, 0, stream>>>(wrow, dwh, dec_b, out);
  else
    k_decode<<<dim3(256, 3), 256, 0, stream>>>(dec_w, dec_b, out);
}

// Round 10
// 260.519 us; speedup vs baseline: 1.5358x; 1.1131x over previous
//
#include <hip/hip_runtime.h>
#include <cfloat>

#define PIXB 1024
static const size_t OFF_Z = 6291456;   // recon = 32*3*256*256
static const size_t OFF_E = 23068672;  // OFF_Z + 32*512*32*32
static const size_t OFF_A = 39845888;  // OFF_E + 32*512*32*32

typedef __attribute__((address_space(1))) const unsigned int cg_u32;
typedef __attribute__((address_space(3))) unsigned int l_u32;
typedef _Float16 f16x8 __attribute__((ext_vector_type(8)));
typedef _Float16 f16x4 __attribute__((ext_vector_type(4)));
typedef float f32x16 __attribute__((ext_vector_type(16)));

#define SPLIT_SCALE 4096.0f
#define SPLIT_INV   (1.0f / 4096.0f)

// ---------------- prep: all weight-side tables ------------------------------
__global__ __launch_bounds__(256) void k_prep(const float* __restrict__ W,
                                              const float* __restrict__ dw,
                                              _Float16* __restrict__ wq,
                                              float* __restrict__ w2,
                                              _Float16* __restrict__ wrow,
                                              _Float16* __restrict__ dwh,
                                              int do_aux) {
  const int t = threadIdx.x;
  const int bx = blockIdx.x;
  __shared__ float T[64][65];
  __shared__ float T2[128][65];
  if (bx < 32) {
    __shared__ float TS[32][260];
    const int cp = bx >> 4, ch = bx & 15;
#pragma unroll
    for (int i = 0; i < 32; ++i)
      TS[i][t] = W[(size_t)(ch * 32 + i) * 512 + cp * 256 + t];
    __syncthreads();
#pragma unroll
    for (int j = 0; j < 4; ++j) {
      const int u = j * 256 + t;
      const int c = u >> 2, slot = u & 3;
      const int se = slot ^ ((c >> 1) & 3);
      f16x8 h, l;
#pragma unroll
      for (int jj = 0; jj < 8; ++jj) {
        const float v = TS[slot * 8 + jj][c];
        const _Float16 hh = (_Float16)v;
        h[jj] = hh;
        l[jj] = (_Float16)((v - (float)hh) * SPLIT_SCALE);
      }
      _Float16* base = wq + cp * 262144 + ch * 16384 + c * 32 + se * 8;
      *(f16x8*)(base) = h;
      *(f16x8*)(base + 8192) = l;
    }
    return;
  }
  if (bx < 34) {
    const int k = (bx - 32) * 256 + t;
    float acc = 0.f;
    for (int d = 0; d < 512; ++d) { const float v = W[(size_t)d * 512 + k]; acc = fmaf(v, v, acc); }
    w2[k] = acc;
    return;
  }
  if (!do_aux) return;
  if (bx < 98) {                 // wrow: transpose W [d][c] -> fp16 [c][d]
    const int id = bx - 34;
    const int c0 = (id & 7) * 64, d0 = (id >> 3) * 64;
#pragma unroll
    for (int i = 0; i < 16; ++i) {
      const int dl = i * 4 + (t >> 6);
      T[dl][t & 63] = W[(size_t)(d0 + dl) * 512 + c0 + (t & 63)];
    }
    __syncthreads();
#pragma unroll
    for (int i = 0; i < 16; ++i) {
      const int cl = i * 4 + (t >> 6);
      const int dl = t & 63;
      wrow[(size_t)(c0 + cl) * 512 + d0 + dl] = (_Float16)T[dl][cl];
    }
    return;
  }
  {                              // dwh: transpose dec_w [d][m] -> fp16 [m][d]
    const int id = bx - 98;
    const int m0 = (id % 3) * 64, d0 = (id / 3) * 128;
#pragma unroll
    for (int i = 0; i < 32; ++i) {
      const int idx = i * 256 + t;
      const int dl = idx >> 6, ml = idx & 63;
      T2[dl][ml] = dw[(size_t)(d0 + dl) * 192 + m0 + ml];
    }
    __syncthreads();
#pragma unroll
    for (int i = 0; i < 32; ++i) {
      const int idx = i * 256 + t;
      const int ml = idx >> 7, dl = idx & 127;
      dwh[(size_t)(m0 + ml) * 512 + d0 + dl] = (_Float16)T2[dl][ml];
    }
  }
}

// ---------------- encode: z_e = conv(x) + b, as GEMM 512x192 @ 192x32768 ----
__global__ __launch_bounds__(256) void k_encode(const float* __restrict__ x,
                                                const float* __restrict__ ew,
                                                const float* __restrict__ eb,
                                                _Float16* __restrict__ zqh,
                                                float* __restrict__ out) {
  __shared__ __align__(16) float Ps[16][68];
  __shared__ __align__(16) float Ws[16][68];
  __shared__ __align__(16) _Float16 ZT[64][80];
  const int n0 = blockIdx.x * 64;
  const int b = n0 / PIXB;
  const int pixbase = n0 % PIXB;
  const int i0 = pixbase >> 5;
  const int c0 = blockIdx.y * 64;
  const int t = threadIdx.x;
  const int tx = t & 15, ty = t >> 4;
  float acc[4][4];
#pragma unroll
  for (int m = 0; m < 4; ++m)
#pragma unroll
    for (int p = 0; p < 4; ++p) acc[m][p] = 0.f;

  const int jj = t >> 3, kjj = t & 7;
  for (int kc = 0; kc < 12; ++kc) {
    const int ci = kc >> 2, kip = kc & 3;
#pragma unroll
    for (int rr = 0; rr < 4; ++rr) {
      const int di = rr >> 1, dki = rr & 1;
      const int row = (i0 + di) * 8 + kip * 2 + dki;
      const float v = x[(((size_t)b * 3 + ci) * 256 + row) * 256 + t];
      Ps[dki * 8 + kjj][di * 32 + jj] = v;
    }
    const int k0 = kc * 16;
#pragma unroll
    for (int ii = 0; ii < 4; ++ii) {
      const int idx = t + ii * 256;
      const int cc = idx >> 4, kk = idx & 15;
      Ws[kk][cc] = ew[(size_t)(c0 + cc) * 192 + k0 + kk];
    }
    __syncthreads();
#pragma unroll
    for (int kk = 0; kk < 16; ++kk) {
      const float4 av = *reinterpret_cast<const float4*>(&Ws[kk][ty * 4]);
      const float4 bv = *reinterpret_cast<const float4*>(&Ps[kk][tx * 4]);
      const float a[4] = {av.x, av.y, av.z, av.w};
      const float bb[4] = {bv.x, bv.y, bv.z, bv.w};
#pragma unroll
      for (int m = 0; m < 4; ++m)
#pragma unroll
        for (int p = 0; p < 4; ++p) acc[m][p] = fmaf(a[m], bb[p], acc[m][p]);
    }
    __syncthreads();
  }
  float zf[4][4];
#pragma unroll
  for (int m = 0; m < 4; ++m) {
    const int c = c0 + ty * 4 + m;
    const float bias = eb[c];
#pragma unroll
    for (int p = 0; p < 4; ++p) zf[m][p] = acc[m][p] + bias;
    float4 v;
    v.x = zf[m][0]; v.y = zf[m][1]; v.z = zf[m][2]; v.w = zf[m][3];
    *reinterpret_cast<float4*>(&out[OFF_Z + ((size_t)b * 512 + c) * 1024 + pixbase + tx * 4]) = v;
  }
#pragma unroll
  for (int s = 0; s < 2; ++s) {
    __syncthreads();
#pragma unroll
    for (int p = 0; p < 4; ++p) {
      f16x4 v;
#pragma unroll
      for (int m = 0; m < 4; ++m) {
        const float f = zf[m][p];
        const _Float16 h = (_Float16)f;
        v[m] = (s == 0) ? h : (_Float16)((f - (float)h) * SPLIT_SCALE);
      }
      *(f16x4*)&ZT[tx * 4 + p][ty * 4] = v;
    }
    __syncthreads();
    _Float16* dst = zqh + (size_t)s * 16777216 +
                    ((size_t)(b * 1024) + pixbase + (t >> 2)) * 512 + c0;
#pragma unroll
    for (int g = 0; g < 2; ++g) {
      const int seg = (t & 3) + g * 4;
      *(f16x8*)(dst + seg * 8) = *(const f16x8*)&ZT[t >> 2][seg * 8];
    }
  }
}

// -------- distance + argmin: counted-vmcnt pipelined MFMA GEMM (T3+T4) ------
// All loop vmem = global_load_lds (exact counts). W triple-buffered (2 ahead,
// L2 ~300cy), z quad-ring (3 ahead, HBM ~900cy). Raw s_barrier (no drain) +
// hand vmcnt(11/10/5/0). z LDS layout uses pre-swizzled GLOBAL source
// (involution slot ^= (p&3)^((p>>2)&3)) with linear staging. MFMA order and
// argmin predicate bit-identical to rounds 5-9 (all passed).
__global__ __launch_bounds__(512) void k_dist(const _Float16* __restrict__ wq,
                                              const _Float16* __restrict__ zq,
                                              const float* __restrict__ w2ws,
                                              float* __restrict__ out) {
  __shared__ __align__(16) unsigned char CB[131072];  // W 3x32KB | z 4x8KB
  __shared__ float WV[512];
  __shared__ int   WI[512];
  const int t = threadIdx.x;
  const int w = t >> 6, lane = t & 63;
  const int wc = w & 3, wp = w >> 2;
  const int n0 = blockIdx.x * 64;
  const int b = n0 >> 10, pixbase = n0 & 1023;
  const int row = lane & 31;
  const int kl16 = (lane >> 5) << 4;

  // A-frag byte offsets within a 32KB W buffer (swizzled, as rounds 8/9)
  int abase[2][2];
#pragma unroll
  for (int ct = 0; ct < 2; ++ct) {
    const int cl = wc * 64 + ct * 32 + row;
    const int sw = ((cl >> 1) & 3) << 4;
#pragma unroll
    for (int ks = 0; ks < 2; ++ks)
      abase[ct][ks] = cl * 64 + (((ks << 5) | kl16) ^ sw);
  }
  // B-frag byte offsets within an 8KB z buffer (h at 0, l at +4096)
  const int p = wp * 32 + row;
  const int zswz = (p & 3) ^ ((p >> 2) & 3);
  const int bb0 = p * 64 + ((((lane >> 5))     ^ zswz) << 4);   // ks=0 slot
  const int bb1 = p * 64 + (((2 | (lane >> 5)) ^ zswz) << 4);   // ks=1 slot

  // z staging source (pre-swizzled): thread t stages one 16B segment
  const int spl = t >> 8, pl = (t & 255) >> 2, seg = t & 3;
  const int sslot = seg ^ ((pl & 3) ^ ((pl >> 2) & 3));
  const _Float16* zsrc = zq + (size_t)spl * 16777216 +
                         ((size_t)(b * 1024) + pixbase + pl) * 512 + sslot * 8;

#define STAGE_W(cpv, chv)                                                        \
  { const _Float16* ws_ = wq + (cpv) * 262144 + (chv) * 16384 + t * 8;           \
    char* wd_ = (char*)CB + ((chv) % 3) * 32768 + t * 16;                        \
    __builtin_amdgcn_global_load_lds((cg_u32*)(ws_),         (l_u32*)(wd_),          16, 0, 0); \
    __builtin_amdgcn_global_load_lds((cg_u32*)(ws_ + 4096),  (l_u32*)(wd_ + 8192),  16, 0, 0); \
    __builtin_amdgcn_global_load_lds((cg_u32*)(ws_ + 8192),  (l_u32*)(wd_ + 16384), 16, 0, 0); \
    __builtin_amdgcn_global_load_lds((cg_u32*)(ws_ + 12288), (l_u32*)(wd_ + 24576), 16, 0, 0); }

#define STAGE_Z(chv)                                                             \
  __builtin_amdgcn_global_load_lds((cg_u32*)(zsrc + (chv) * 32),                 \
      (l_u32*)((char*)CB + 98304 + ((chv) & 3) * 8192 + t * 16), 16, 0, 0);

#define COMPUTE(chv)                                                             \
  { const char* wb_ = (const char*)CB + ((chv) % 3) * 32768;                     \
    const char* zb_ = (const char*)CB + 98304 + ((chv) & 3) * 8192;              \
    const f16x8 Bh0 = *(const f16x8*)(zb_ + bb0);                                \
    const f16x8 Bh1 = *(const f16x8*)(zb_ + bb1);                                \
    const f16x8 Bl0 = *(const f16x8*)(zb_ + 4096 + bb0);                         \
    const f16x8 Bl1 = *(const f16x8*)(zb_ + 4096 + bb1);                         \
    __builtin_amdgcn_s_setprio(1);                                               \
    _Pragma("unroll")                                                            \
    for (int ct_ = 0; ct_ < 2; ++ct_) {                                          \
      const f16x8 Ah0 = *(const f16x8*)(wb_ + abase[ct_][0]);                    \
      const f16x8 Al0 = *(const f16x8*)(wb_ + 16384 + abase[ct_][0]);            \
      const f16x8 Ah1 = *(const f16x8*)(wb_ + abase[ct_][1]);                    \
      const f16x8 Al1 = *(const f16x8*)(wb_ + 16384 + abase[ct_][1]);            \
      accA[ct_] = __builtin_amdgcn_mfma_f32_32x32x16_f16(Ah0, Bh0, accA[ct_], 0, 0, 0); \
      accB[ct_] = __builtin_amdgcn_mfma_f32_32x32x16_f16(Ah0, Bl0, accB[ct_], 0, 0, 0); \
      accB[ct_] = __builtin_amdgcn_mfma_f32_32x32x16_f16(Al0, Bh0, accB[ct_], 0, 0, 0); \
      accA[ct_] = __builtin_amdgcn_mfma_f32_32x32x16_f16(Ah1, Bh1, accA[ct_], 0, 0, 0); \
      accB[ct_] = __builtin_amdgcn_mfma_f32_32x32x16_f16(Ah1, Bl1, accB[ct_], 0, 0, 0); \
      accB[ct_] = __builtin_amdgcn_mfma_f32_32x32x16_f16(Al1, Bh1, accB[ct_], 0, 0, 0); \
    }                                                                            \
    __builtin_amdgcn_s_setprio(0); }

#define PHASE(chv, waitlit)                                                      \
  { asm volatile("s_waitcnt vmcnt(" #waitlit ")" ::: "memory");                  \
    __builtin_amdgcn_sched_barrier(0);                                           \
    __builtin_amdgcn_s_barrier();                                                \
    COMPUTE(chv);                                                                \
    __builtin_amdgcn_s_barrier(); }

  float bv = FLT_MAX; int bi = 0x7fffffff;

#pragma unroll 1
  for (int cp = 0; cp < 2; ++cp) {
    f32x16 accA[2], accB[2];
#pragma unroll
    for (int ct = 0; ct < 2; ++ct) { accA[ct] = (f32x16)(0.0f); accB[ct] = (f32x16)(0.0f); }
    // prologue: W(0),W(1) staged; z(0),z(1),z(2) staged
    STAGE_W(cp, 0); STAGE_Z(0);
    STAGE_W(cp, 1); STAGE_Z(1);
    STAGE_Z(2);
#pragma unroll 1
    for (int ch = 0; ch < 13; ++ch) {
      STAGE_W(cp, ch + 2);
      STAGE_Z(ch + 3);
      PHASE(ch, 11);       // newer: W(ch+1),W(ch+2)=8 + z(ch+1..ch+3)=3
    }
    STAGE_W(cp, 15);
    PHASE(13, 10);         // newer: W(14),W(15)=8 + z(14),z(15)=2
    PHASE(14, 5);          // newer: W(15)=4 + z(15)=1
    PHASE(15, 0);

    // ---- per-pass d2 + argmin update (order identical to rounds 5-9) ----
#pragma unroll
    for (int ct = 0; ct < 2; ++ct) {
#pragma unroll
      for (int r = 0; r < 16; ++r) {
        const int code = cp * 256 + wc * 64 + ct * 32 +
                         ((r & 3) + ((r >> 2) << 3) + ((lane >> 5) << 2));
        const float zw = fmaf(accB[ct][r], SPLIT_INV, accA[ct][r]);
        const float d2 = fmaf(-2.f, zw, w2ws[code]);
        if (d2 < bv || (d2 == bv && code < bi)) { bv = d2; bi = code; }
      }
    }
  }

  WV[w * 64 + lane] = bv;
  WI[w * 64 + lane] = bi;
  __syncthreads();
  if (t < 64) {
    const int pw = t >> 5;
    float fbv = FLT_MAX; int fbi = 0x7fffffff;
#pragma unroll
    for (int wcc = 0; wcc < 4; ++wcc)
#pragma unroll
      for (int hh = 0; hh < 2; ++hh) {
        const int li = (pw * 4 + wcc) * 64 + (t & 31) + hh * 32;
        const float v = WV[li];
        const int ii = WI[li];
        if (v < fbv || (v == fbv && ii < fbi)) { fbv = v; fbi = ii; }
      }
    out[OFF_A + n0 + t] = (float)fbi;
  }
#undef STAGE_W
#undef STAGE_Z
#undef COMPUTE
#undef PHASE
}

// ---------------- gather: emb[d][pix] = W[d][argmin[pix]] -------------------
__global__ __launch_bounds__(256) void k_gather(const float* __restrict__ Wc,
                                                float* __restrict__ out) {
  const int n0 = blockIdx.x * 32;
  const int b = n0 >> 10, pixbase = n0 & 1023;
  const int t = threadIdx.x;
  const int pix = t & 31;
  const int kidx = (int)out[OFF_A + n0 + pix];
  for (int d = t >> 5; d < 512; d += 8)
    out[OFF_E + ((size_t)(b * 512 + d)) * 1024 + pixbase + pix] = Wc[(size_t)d * 512 + kidx];
}

// -------- decode via single-fp16 MFMA (q in (-0.04,0.04), err ~2e-5) --------
__global__ __launch_bounds__(512) void k_decmfma(const _Float16* __restrict__ wrow,
                                                 const _Float16* __restrict__ dwh,
                                                 const float* __restrict__ db,
                                                 float* __restrict__ out) {
  __shared__ __align__(16) _Float16 QB[2][4096];
  __shared__ int KIDX[128];
  const int t = threadIdx.x;
  const int w = t >> 6, lane = t & 63;
  const int pt = w & 3, mg = w >> 2;
  const int blk = blockIdx.x;
  const int b = blk >> 3;
  const int pixbase = (blk & 7) * 128;
  if (t < 128) KIDX[t] = (int)out[OFF_A + b * 1024 + pixbase + t];
  __syncthreads();
  const int pixS = t >> 2, slotS = t & 3;
  const _Float16* qsrc = wrow + (size_t)KIDX[pixS] * 512 + slotS * 8;
  const int ldsW = pixS * 32 + (slotS ^ ((pixS >> 1) & 3)) * 8;

  const _Float16* ab[3];
#pragma unroll
  for (int mt = 0; mt < 3; ++mt)
    ab[mt] = dwh + (size_t)((mg * 3 + mt) * 32 + (lane & 31)) * 512 + ((lane >> 5) << 3);

  const int brow = pt * 32 + (lane & 31);
  const int bsw = (brow >> 1) & 3;
  int boff[2];
#pragma unroll
  for (int ks = 0; ks < 2; ++ks)
    boff[ks] = brow * 32 + (((ks * 2 + (lane >> 5)) ^ bsw)) * 8;

  f32x16 acc[3];
#pragma unroll
  for (int mt = 0; mt < 3; ++mt) acc[mt] = (f32x16)(0.0f);
  f16x8 A[2][3][2];
  f16x8 qd[2];

  qd[0] = *(const f16x8*)(qsrc);
#pragma unroll
  for (int mt = 0; mt < 3; ++mt)
#pragma unroll
    for (int ks = 0; ks < 2; ++ks)
      A[0][mt][ks] = *(const f16x8*)(ab[mt] + ks * 16);
  *(f16x8*)&QB[0][ldsW] = qd[0];
  qd[1] = *(const f16x8*)(qsrc + 32);
  __syncthreads();

#pragma unroll
  for (int ch = 0; ch < 16; ++ch) {
    const int par = ch & 1;
    if (ch < 15) {
      *(f16x8*)&QB[par ^ 1][ldsW] = qd[(ch + 1) & 1];
#pragma unroll
      for (int mt = 0; mt < 3; ++mt)
#pragma unroll
        for (int ks = 0; ks < 2; ++ks)
          A[par ^ 1][mt][ks] = *(const f16x8*)(ab[mt] + (ch + 1) * 32 + ks * 16);
    }
    if (ch < 14) qd[ch & 1] = *(const f16x8*)(qsrc + (ch + 2) * 32);
    const f16x8 B0 = *(const f16x8*)&QB[par][boff[0]];
    const f16x8 B1 = *(const f16x8*)&QB[par][boff[1]];
#pragma unroll
    for (int mt = 0; mt < 3; ++mt) {
      acc[mt] = __builtin_amdgcn_mfma_f32_32x32x16_f16(A[par][mt][0], B0, acc[mt], 0, 0, 0);
      acc[mt] = __builtin_amdgcn_mfma_f32_32x32x16_f16(A[par][mt][1], B1, acc[mt], 0, 0, 0);
    }
    __syncthreads();
  }

  const float b0 = db[0], b1 = db[1], b2 = db[2];
  const int pix = pixbase + pt * 32 + (lane & 31);
  const int i = pix >> 5, j = pix & 31;
#pragma unroll
  for (int mt = 0; mt < 3; ++mt) {
    const int m0 = (mg * 3 + mt) * 32;
#pragma unroll
    for (int r = 0; r < 16; ++r) {
      const int m = m0 + (r & 3) + ((r >> 2) << 3) + ((lane >> 5) << 2);
      const int c = m >> 6, ki = (m >> 3) & 7, kj = m & 7;
      const float bias = (c == 0) ? b0 : ((c == 1) ? b1 : b2);
      out[(((size_t)b * 3 + c) * 256 + i * 8 + 7 - ki) * 256 + j * 8 + 7 - kj] = acc[mt][r] + bias;
    }
  }
}

// ---------------- decode fallback: fp32 VALU (if ws too small) --------------
__global__ __launch_bounds__(256) void k_decode(const float* __restrict__ dw,
                                                const float* __restrict__ db,
                                                float* out) {
  __shared__ __align__(16) float Qs[32][132];
  __shared__ __align__(16) float Ws3[32][68];
  const int n0 = blockIdx.x * 128;
  const int b = n0 / PIXB, pixbase = n0 % PIXB;
  const int mt = blockIdx.y;
  const int t = threadIdx.x;
  const int pg = t & 31, ck = t >> 5;
  float acc[4][8];
#pragma unroll
  for (int p = 0; p < 4; ++p)
#pragma unroll
    for (int k = 0; k < 8; ++k) acc[p][k] = 0.f;
  for (int dc = 0; dc < 16; ++dc) {
#pragma unroll
    for (int ii = 0; ii < 4; ++ii) {
      const int id = t + ii * 256;
      const int dd = id >> 5, p4 = id & 31;
      *reinterpret_cast<float4*>(&Qs[dd][p4 * 4]) =
        *reinterpret_cast<const float4*>(&out[OFF_E + ((size_t)b * 512 + dc * 32 + dd) * 1024 + pixbase + p4 * 4]);
    }
#pragma unroll
    for (int ii = 0; ii < 2; ++ii) {
      const int id = t + ii * 256;
      const int dd = id >> 4, m4 = id & 15;
      *reinterpret_cast<float4*>(&Ws3[dd][m4 * 4]) =
        *reinterpret_cast<const float4*>(&dw[(size_t)(dc * 32 + dd) * 192 + mt * 64 + m4 * 4]);
    }
    __syncthreads();
#pragma unroll
    for (int dd = 0; dd < 32; ++dd) {
      const float4 qv = *reinterpret_cast<const float4*>(&Qs[dd][pg * 4]);
      const float4 wa = *reinterpret_cast<const float4*>(&Ws3[dd][ck * 8]);
      const float4 wb = *reinterpret_cast<const float4*>(&Ws3[dd][ck * 8 + 4]);
      const float q[4] = {qv.x, qv.y, qv.z, qv.w};
      const float wv[8] = {wa.x, wa.y, wa.z, wa.w, wb.x, wb.y, wb.z, wb.w};
#pragma unroll
      for (int p = 0; p < 4; ++p)
#pragma unroll
        for (int k = 0; k < 8; ++k) acc[p][k] = fmaf(q[p], wv[k], acc[p][k]);
    }
    __syncthreads();
  }
  const int ckg = mt * 8 + ck;
  const int c = ckg >> 3, ki = ckg & 7;
  const float bias = db[c];
#pragma unroll
  for (int p = 0; p < 4; ++p) {
    const int pix = pixbase + pg * 4 + p;
    const int i = pix >> 5, j = pix & 31;
    const size_t base = (((size_t)b * 3 + c) * 256 + i * 8 + 7 - ki) * 256 + j * 8;
#pragma unroll
    for (int kj = 0; kj < 8; ++kj) out[base + 7 - kj] = acc[p][kj] + bias;
  }
}

extern "C" void kernel_launch(void* const* d_in, const int* in_sizes, int n_in,
                              void* d_out, int out_size, void* d_ws, size_t ws_size,
                              hipStream_t stream) {
  const float* x     = (const float*)d_in[0];
  const float* enc_w = (const float*)d_in[1];
  const float* enc_b = (const float*)d_in[2];
  const float* dec_w = (const float*)d_in[3];
  const float* dec_b = (const float*)d_in[4];
  const float* emb_w = (const float*)d_in[5];
  float* out = (float*)d_out;
  float* w2 = (float*)d_ws;                              // 2KB
  _Float16* wrow = (_Float16*)((char*)d_ws + 2048);      // 512KB
  _Float16* dwh  = (_Float16*)((char*)d_ws + 2048 + 524288);  // 192KB
  const int do_aux = (ws_size >= (size_t)(2048 + 524288 + 196608)) ? 1 : 0;
  _Float16* wq  = (_Float16*)d_out;                      // 1MB in recon region
  _Float16* zqh = (_Float16*)((char*)d_out + 92274688);  // zq splits in emb region

  k_prep<<<110, 256, 0, stream>>>(emb_w, dec_w, wq, w2, wrow, dwh, do_aux);
  k_encode<<<dim3(512, 8), 256, 0, stream>>>(x, enc_w, enc_b, zqh, out);
  k_dist<<<512, 512, 0, stream>>>(wq, zqh, w2, out);
  k_gather<<<1024, 256, 0, stream>>>(emb_w, out);
  if (do_aux)
    k_decmfma<<<256, 512, 0, stream>>>(wrow, dwh, dec_b, out);
  else
    k_decode<<<dim3(256, 3), 256, 0, stream>>>(dec_w, dec_b, out);
}

// Round 11
// 208.373 us; speedup vs baseline: 1.9202x; 1.2503x over previous
//
#include <hip/hip_runtime.h>
#include <cfloat>

#define PIXB 1024
static const size_t OFF_Z = 6291456;   // recon = 32*3*256*256
static const size_t OFF_E = 23068672;  // OFF_Z + 32*512*32*32
static const size_t OFF_A = 39845888;  // OFF_E + 32*512*32*32

typedef __attribute__((address_space(1))) const unsigned int cg_u32;
typedef __attribute__((address_space(3))) unsigned int l_u32;
typedef _Float16 f16x8 __attribute__((ext_vector_type(8)));
typedef _Float16 f16x4 __attribute__((ext_vector_type(4)));
typedef float f32x16 __attribute__((ext_vector_type(16)));

#define SPLIT_SCALE 4096.0f
#define SPLIT_INV   (1.0f / 4096.0f)

#define GL16(srcp, dstp) __builtin_amdgcn_global_load_lds((cg_u32*)(srcp), (l_u32*)(dstp), 16, 0, 0)

// ---------------- prep: all weight-side tables ------------------------------
// bx 0..31  : wq chunk-images (k_dist A, swizzled; recon region)
// bx 32..33 : w2 (d_ws)
// bx 34..45 : aq chunk-images (encode A, swizzled; recon region +2MB)
// bx 46..109: wrow [code][d] fp16 (decode gather table, d_ws)  [do_aux]
// bx 110..121: dwh [m 192][d] fp16 (decode A, d_ws)            [do_aux]
__global__ __launch_bounds__(256) void k_prep(const float* __restrict__ W,
                                              const float* __restrict__ dw,
                                              const float* __restrict__ ew,
                                              _Float16* __restrict__ wq,
                                              float* __restrict__ w2,
                                              _Float16* __restrict__ aq,
                                              _Float16* __restrict__ wrow,
                                              _Float16* __restrict__ dwh,
                                              int do_aux) {
  const int t = threadIdx.x;
  const int bx = blockIdx.x;
  __shared__ float T[64][65];
  __shared__ float T2[128][65];
  if (bx < 32) {
    __shared__ float TS[32][260];
    const int cp = bx >> 4, ch = bx & 15;
#pragma unroll
    for (int i = 0; i < 32; ++i)
      TS[i][t] = W[(size_t)(ch * 32 + i) * 512 + cp * 256 + t];
    __syncthreads();
#pragma unroll
    for (int j = 0; j < 4; ++j) {
      const int u = j * 256 + t;
      const int c = u >> 2, slot = u & 3;
      const int se = slot ^ ((c >> 1) & 3);
      f16x8 h, l;
#pragma unroll
      for (int jj = 0; jj < 8; ++jj) {
        const float v = TS[slot * 8 + jj][c];
        const _Float16 hh = (_Float16)v;
        h[jj] = hh;
        l[jj] = (_Float16)((v - (float)hh) * SPLIT_SCALE);
      }
      _Float16* base = wq + cp * 262144 + ch * 16384 + c * 32 + se * 8;
      *(f16x8*)(base) = h;
      *(f16x8*)(base + 8192) = l;
    }
    return;
  }
  if (bx < 34) {
    const int k = (bx - 32) * 256 + t;
    float acc = 0.f;
    for (int d = 0; d < 512; ++d) { const float v = W[(size_t)d * 512 + k]; acc = fmaf(v, v, acc); }
    w2[k] = acc;
    return;
  }
  if (bx < 46) {                 // aq: enc_w [c][192] -> chunk images [ch 12][spl][c 512][se 2][8]
    const int ch = bx - 34;
#pragma unroll
    for (int cc = 0; cc < 2; ++cc) {
      const int c = cc * 256 + t;
      const float* src = ew + (size_t)c * 192 + ch * 16;
#pragma unroll
      for (int slot = 0; slot < 2; ++slot) {
        f16x8 h, l;
#pragma unroll
        for (int j = 0; j < 8; ++j) {
          const float v = src[slot * 8 + j];
          const _Float16 hh = (_Float16)v;
          h[j] = hh;
          l[j] = (_Float16)((v - (float)hh) * SPLIT_SCALE);
        }
        const int se = slot ^ ((c >> 2) & 1);
        _Float16* dst = aq + (size_t)ch * 16384 + c * 16 + se * 8;
        *(f16x8*)dst = h;
        *(f16x8*)(dst + 8192) = l;
      }
    }
    return;
  }
  if (!do_aux) return;
  if (bx < 110) {                // wrow: transpose W [d][c] -> fp16 [c][d]
    const int id = bx - 46;
    const int c0 = (id & 7) * 64, d0 = (id >> 3) * 64;
#pragma unroll
    for (int i = 0; i < 16; ++i) {
      const int dl = i * 4 + (t >> 6);
      T[dl][t & 63] = W[(size_t)(d0 + dl) * 512 + c0 + (t & 63)];
    }
    __syncthreads();
#pragma unroll
    for (int i = 0; i < 16; ++i) {
      const int cl = i * 4 + (t >> 6);
      const int dl = t & 63;
      wrow[(size_t)(c0 + cl) * 512 + d0 + dl] = (_Float16)T[dl][cl];
    }
    return;
  }
  {                              // dwh: transpose dec_w [d][m] -> fp16 [m][d]
    const int id = bx - 110;
    const int m0 = (id % 3) * 64, d0 = (id / 3) * 128;
#pragma unroll
    for (int i = 0; i < 32; ++i) {
      const int idx = i * 256 + t;
      const int dl = idx >> 6, ml = idx & 63;
      T2[dl][ml] = dw[(size_t)(d0 + dl) * 192 + m0 + ml];
    }
    __syncthreads();
#pragma unroll
    for (int i = 0; i < 32; ++i) {
      const int idx = i * 256 + t;
      const int ml = idx >> 7, dl = idx & 127;
      dwh[(size_t)(m0 + ml) * 512 + d0 + dl] = (_Float16)T2[dl][ml];
    }
  }
}

// -------- encode via MFMA (fp16 2-split, 3 products), counted-vmcnt ---------
// Block: 64 pix x 512 ch, 8 waves (wc = w&3 ch-slice of 128, wp = w>>2 pixel
// half). A = aq chunk-images (L2, global_load_lds, triple buffer, 2 ahead);
// B = raw x rows (4KB tile dup x2, involution-permuted source, ring 4,
// 3 ahead) + in-register fp16 split. Same phase/vmcnt discipline as k_dist
// (5 loads/thread/chunk -> 11/10/5/0). Epilogue: z_e fp32 (coalesced) + zq2
// octet-major [spl][g][pix][8] via LDS bounce (coalesced 16B stores).
__global__ __launch_bounds__(512) void k_encmfma(const float* __restrict__ x,
                                                 const _Float16* __restrict__ aq,
                                                 const float* __restrict__ eb,
                                                 _Float16* __restrict__ zq2,
                                                 float* __restrict__ out) {
  __shared__ __align__(16) unsigned char CB[131072];  // A 3x32KB | B 4x8KB; epilogue: ZB 128KB
  __shared__ float ebL[512];
  const int t = threadIdx.x;
  ebL[t] = eb[t];
  const int w = t >> 6, lane = t & 63;
  const int wc = w & 3, wp = w >> 2;
  const int n0 = blockIdx.x * 64;
  const int b = n0 >> 10, pixbase = n0 & 1023;
  const int i0 = pixbase >> 5;
  const int row = lane & 31, hi = lane >> 5;

  int ab[4];
#pragma unroll
  for (int ct = 0; ct < 4; ++ct) {
    const int c = wc * 128 + ct * 32 + row;
    ab[ct] = c * 32 + ((hi ^ ((c >> 2) & 1)) << 4);
  }
  // B staging: t = copy*256 + srow*64 + vsl; source col = involution(vsl)
  const int u = t & 255, srow = u >> 6, vsl = u & 63;
  const int csrc = vsl ^ ((vsl >> 3) & 1);
  const float* xb = x + ((size_t)b * 3 * 256 + (i0 + (srow >> 1)) * 8 + (srow & 1)) * 256 + csrc * 4;
  // B reader: j = pixel col; slots (2j+s) ^ ((j>>2)&1); tile row = wp*2+hi, copy = wp
  const int bv0 = (((2 * row) ^ ((row >> 2) & 1)) << 4);
  const int bv1 = (((2 * row + 1) ^ ((row >> 2) & 1)) << 4);
  const int brb = wp * 4096 + (wp * 2 + hi) * 1024;

  f32x16 accA[4], accB[4];
#pragma unroll
  for (int ct = 0; ct < 4; ++ct) { accA[ct] = (f32x16)(0.0f); accB[ct] = (f32x16)(0.0f); }

#define STAGE_A(chv) { const _Float16* as_ = aq + (size_t)(chv) * 16384 + t * 8;            \
    char* ad_ = (char*)CB + ((chv) % 3) * 32768 + t * 16;                                   \
    GL16(as_, ad_); GL16(as_ + 4096, ad_ + 8192);                                           \
    GL16(as_ + 8192, ad_ + 16384); GL16(as_ + 12288, ad_ + 24576); }
#define STAGE_B(chv) GL16(xb + (((chv) >> 2) * 65536 + ((chv) & 3) * 512),                  \
                          (char*)CB + 98304 + (((chv) & 3)) * 8192 + t * 16)
#define ECOMP(chv)                                                                          \
  { const char* abuf = (const char*)CB + ((chv) % 3) * 32768;                               \
    const char* bbuf = (const char*)CB + 98304 + ((chv) & 3) * 8192 + brb;                  \
    const float4 xa = *(const float4*)(bbuf + bv0);                                         \
    const float4 xc = *(const float4*)(bbuf + bv1);                                         \
    const float xs[8] = {xa.x, xa.y, xa.z, xa.w, xc.x, xc.y, xc.z, xc.w};                   \
    f16x8 Bh, Bl;                                                                           \
    _Pragma("unroll") for (int q = 0; q < 8; ++q) {                                         \
      const _Float16 hh = (_Float16)xs[q];                                                  \
      Bh[q] = hh; Bl[q] = (_Float16)((xs[q] - (float)hh) * SPLIT_SCALE); }                  \
    __builtin_amdgcn_s_setprio(1);                                                          \
    _Pragma("unroll") for (int ct_ = 0; ct_ < 4; ++ct_) {                                   \
      const f16x8 Ah = *(const f16x8*)(abuf + ab[ct_]);                                     \
      const f16x8 Al = *(const f16x8*)(abuf + 16384 + ab[ct_]);                             \
      accA[ct_] = __builtin_amdgcn_mfma_f32_32x32x16_f16(Ah, Bh, accA[ct_], 0, 0, 0);       \
      accB[ct_] = __builtin_amdgcn_mfma_f32_32x32x16_f16(Ah, Bl, accB[ct_], 0, 0, 0);       \
      accB[ct_] = __builtin_amdgcn_mfma_f32_32x32x16_f16(Al, Bh, accB[ct_], 0, 0, 0); }     \
    __builtin_amdgcn_s_setprio(0); }
#define EPHASE(chv, waitlit)                                                                \
  { asm volatile("s_waitcnt vmcnt(" #waitlit ")" ::: "memory");                             \
    __builtin_amdgcn_sched_barrier(0);                                                      \
    __builtin_amdgcn_s_barrier();                                                           \
    ECOMP(chv);                                                                             \
    __builtin_amdgcn_s_barrier(); }

  STAGE_A(0); STAGE_B(0);
  STAGE_A(1); STAGE_B(1);
  STAGE_B(2);
#pragma unroll 1
  for (int ch = 0; ch < 9; ++ch) {
    STAGE_A(ch + 2);
    STAGE_B(ch + 3);
    EPHASE(ch, 11);
  }
  STAGE_A(11);
  EPHASE(9, 10);
  EPHASE(10, 5);
  EPHASE(11, 0);
#undef STAGE_A
#undef STAGE_B
#undef ECOMP
#undef EPHASE

  // ---- epilogue: z_e (fp32, coalesced) + zq2 splits via LDS bounce ----
  __syncthreads();
  _Float16* ZB = (_Float16*)CB;    // [spl 2][pix 64][c 512] halves = 128KB
  const int pl = wp * 32 + row;
#pragma unroll
  for (int ct = 0; ct < 4; ++ct) {
    float zv[16];
#pragma unroll
    for (int r = 0; r < 16; ++r) {
      const int c = wc * 128 + ct * 32 + (r & 3) + ((r >> 2) << 3) + (hi << 2);
      zv[r] = fmaf(accB[ct][r], SPLIT_INV, accA[ct][r]) + ebL[c];
      out[OFF_Z + ((size_t)(b * 512 + c)) * 1024 + pixbase + pl] = zv[r];
    }
#pragma unroll
    for (int rq = 0; rq < 4; ++rq) {
      f16x4 vh, vl;
#pragma unroll
      for (int q = 0; q < 4; ++q) {
        const float f = zv[rq * 4 + q];
        const _Float16 hh = (_Float16)f;
        vh[q] = hh;
        vl[q] = (_Float16)((f - (float)hh) * SPLIT_SCALE);
      }
      const int c4 = wc * 128 + ct * 32 + (rq << 3) + (hi << 2);
      const int off = pl * 1024 + ((c4 * 2) ^ ((pl & 7) << 4));
      *(f16x4*)((char*)ZB + off) = vh;
      *(f16x4*)((char*)ZB + 65536 + off) = vl;
    }
  }
  __syncthreads();
#pragma unroll
  for (int spl = 0; spl < 2; ++spl)
#pragma unroll
    for (int gg = 0; gg < 8; ++gg) {
      const int g = w * 8 + gg;
      const f16x8 vv = *(const f16x8*)((char*)ZB + spl * 65536 + lane * 1024 + ((g * 16) ^ ((lane & 7) << 4)));
      *(f16x8*)(zq2 + ((size_t)(spl * 64 + g) * 32768 + b * 1024 + pixbase + lane) * 8) = vv;
    }
}

// -------- distance + argmin: counted-vmcnt pipelined MFMA GEMM --------------
// As round 10 (which removed k_dist from the hot list), with zq2 octet-major
// layout: z staging source contiguous, B-frag LDS reads conflict-free.
// MFMA order and argmin predicate unchanged.
__global__ __launch_bounds__(512) void k_dist(const _Float16* __restrict__ wq,
                                              const _Float16* __restrict__ zq,
                                              const float* __restrict__ w2ws,
                                              float* __restrict__ out) {
  __shared__ __align__(16) unsigned char CB[131072];  // W 3x32KB | z 4x8KB
  __shared__ float WV[512];
  __shared__ int   WI[512];
  const int t = threadIdx.x;
  const int w = t >> 6, lane = t & 63;
  const int wc = w & 3, wp = w >> 2;
  const int n0 = blockIdx.x * 64;
  const int b = n0 >> 10, pixbase = n0 & 1023;
  const int row = lane & 31, hi = lane >> 5;
  const int kl16 = hi << 4;
  const int pl = wp * 32 + row;

  int abase[2][2];
#pragma unroll
  for (int ct = 0; ct < 2; ++ct) {
    const int cl = wc * 64 + ct * 32 + row;
    const int sw = ((cl >> 1) & 3) << 4;
#pragma unroll
    for (int ks = 0; ks < 2; ++ks)
      abase[ct][ks] = cl * 64 + (((ks << 5) | kl16) ^ sw);
  }
  // z staging: t = spl*256 + gl*64 + pixl
  const _Float16* zsrc0 = zq + ((size_t)((t >> 8) * 64 + ((t >> 6) & 3)) * 32768 +
                                b * 1024 + pixbase + (t & 63)) * 8;

#define STAGE_W(cpv, chv)                                                        \
  { const _Float16* ws_ = wq + (cpv) * 262144 + (chv) * 16384 + t * 8;           \
    char* wd_ = (char*)CB + ((chv) % 3) * 32768 + t * 16;                        \
    GL16(ws_, wd_); GL16(ws_ + 4096, wd_ + 8192);                                \
    GL16(ws_ + 8192, wd_ + 16384); GL16(ws_ + 12288, wd_ + 24576); }
#define STAGE_Z(chv)                                                             \
  GL16(zsrc0 + (size_t)(chv) * 1048576,                                          \
       (char*)CB + 98304 + ((chv) & 3) * 8192 + t * 16)
#define COMPUTE(chv)                                                             \
  { const char* wb_ = (const char*)CB + ((chv) % 3) * 32768;                     \
    const char* zb_ = (const char*)CB + 98304 + ((chv) & 3) * 8192;              \
    const f16x8 Bh0 = *(const f16x8*)(zb_ + hi * 1024 + pl * 16);                \
    const f16x8 Bh1 = *(const f16x8*)(zb_ + (2 + hi) * 1024 + pl * 16);          \
    const f16x8 Bl0 = *(const f16x8*)(zb_ + 4096 + hi * 1024 + pl * 16);         \
    const f16x8 Bl1 = *(const f16x8*)(zb_ + 4096 + (2 + hi) * 1024 + pl * 16);   \
    __builtin_amdgcn_s_setprio(1);                                               \
    _Pragma("unroll")                                                            \
    for (int ct_ = 0; ct_ < 2; ++ct_) {                                          \
      const f16x8 Ah0 = *(const f16x8*)(wb_ + abase[ct_][0]);                    \
      const f16x8 Al0 = *(const f16x8*)(wb_ + 16384 + abase[ct_][0]);            \
      const f16x8 Ah1 = *(const f16x8*)(wb_ + abase[ct_][1]);                    \
      const f16x8 Al1 = *(const f16x8*)(wb_ + 16384 + abase[ct_][1]);            \
      accA[ct_] = __builtin_amdgcn_mfma_f32_32x32x16_f16(Ah0, Bh0, accA[ct_], 0, 0, 0); \
      accB[ct_] = __builtin_amdgcn_mfma_f32_32x32x16_f16(Ah0, Bl0, accB[ct_], 0, 0, 0); \
      accB[ct_] = __builtin_amdgcn_mfma_f32_32x32x16_f16(Al0, Bh0, accB[ct_], 0, 0, 0); \
      accA[ct_] = __builtin_amdgcn_mfma_f32_32x32x16_f16(Ah1, Bh1, accA[ct_], 0, 0, 0); \
      accB[ct_] = __builtin_amdgcn_mfma_f32_32x32x16_f16(Ah1, Bl1, accB[ct_], 0, 0, 0); \
      accB[ct_] = __builtin_amdgcn_mfma_f32_32x32x16_f16(Al1, Bh1, accB[ct_], 0, 0, 0); \
    }                                                                            \
    __builtin_amdgcn_s_setprio(0); }
#define PHASE(chv, waitlit)                                                      \
  { asm volatile("s_waitcnt vmcnt(" #waitlit ")" ::: "memory");                  \
    __builtin_amdgcn_sched_barrier(0);                                           \
    __builtin_amdgcn_s_barrier();                                                \
    COMPUTE(chv);                                                                \
    __builtin_amdgcn_s_barrier(); }

  float bv = FLT_MAX; int bi = 0x7fffffff;

#pragma unroll 1
  for (int cp = 0; cp < 2; ++cp) {
    f32x16 accA[2], accB[2];
#pragma unroll
    for (int ct = 0; ct < 2; ++ct) { accA[ct] = (f32x16)(0.0f); accB[ct] = (f32x16)(0.0f); }
    STAGE_W(cp, 0); STAGE_Z(0);
    STAGE_W(cp, 1); STAGE_Z(1);
    STAGE_Z(2);
#pragma unroll 1
    for (int ch = 0; ch < 13; ++ch) {
      STAGE_W(cp, ch + 2);
      STAGE_Z(ch + 3);
      PHASE(ch, 11);
    }
    STAGE_W(cp, 15);
    PHASE(13, 10);
    PHASE(14, 5);
    PHASE(15, 0);

#pragma unroll
    for (int ct = 0; ct < 2; ++ct) {
#pragma unroll
      for (int r = 0; r < 16; ++r) {
        const int code = cp * 256 + wc * 64 + ct * 32 +
                         ((r & 3) + ((r >> 2) << 3) + (hi << 2));
        const float zw = fmaf(accB[ct][r], SPLIT_INV, accA[ct][r]);
        const float d2 = fmaf(-2.f, zw, w2ws[code]);
        if (d2 < bv || (d2 == bv && code < bi)) { bv = d2; bi = code; }
      }
    }
  }
#undef STAGE_W
#undef STAGE_Z
#undef COMPUTE
#undef PHASE

  WV[w * 64 + lane] = bv;
  WI[w * 64 + lane] = bi;
  __syncthreads();
  if (t < 64) {
    const int pw = t >> 5;
    float fbv = FLT_MAX; int fbi = 0x7fffffff;
#pragma unroll
    for (int wcc = 0; wcc < 4; ++wcc)
#pragma unroll
      for (int hh = 0; hh < 2; ++hh) {
        const int li = (pw * 4 + wcc) * 64 + (t & 31) + hh * 32;
        const float v = WV[li];
        const int ii = WI[li];
        if (v < fbv || (v == fbv && ii < fbi)) { fbv = v; fbi = ii; }
      }
    out[OFF_A + n0 + t] = (float)fbi;
  }
}

// ---------------- gather: emb[d][pix] = W[d][argmin[pix]] -------------------
__global__ __launch_bounds__(256) void k_gather(const float* __restrict__ Wc,
                                                float* __restrict__ out) {
  const int n0 = blockIdx.x * 32;
  const int b = n0 >> 10, pixbase = n0 & 1023;
  const int t = threadIdx.x;
  const int pix = t & 31;
  const int kidx = (int)out[OFF_A + n0 + pix];
  for (int d = t >> 5; d < 512; d += 8)
    out[OFF_E + ((size_t)(b * 512 + d)) * 1024 + pixbase + pix] = Wc[(size_t)d * 512 + kidx];
}

// -------- decode via single-fp16 MFMA (q in (-0.04,0.04), err ~2e-5) --------
__global__ __launch_bounds__(512) void k_decmfma(const _Float16* __restrict__ wrow,
                                                 const _Float16* __restrict__ dwh,
                                                 const float* __restrict__ db,
                                                 float* __restrict__ out) {
  __shared__ __align__(16) _Float16 QB[2][4096];
  __shared__ int KIDX[128];
  const int t = threadIdx.x;
  const int w = t >> 6, lane = t & 63;
  const int pt = w & 3, mg = w >> 2;
  const int blk = blockIdx.x;
  const int b = blk >> 3;
  const int pixbase = (blk & 7) * 128;
  if (t < 128) KIDX[t] = (int)out[OFF_A + b * 1024 + pixbase + t];
  __syncthreads();
  const int pixS = t >> 2, slotS = t & 3;
  const _Float16* qsrc = wrow + (size_t)KIDX[pixS] * 512 + slotS * 8;
  const int ldsW = pixS * 32 + (slotS ^ ((pixS >> 1) & 3)) * 8;

  const _Float16* abp[3];
#pragma unroll
  for (int mt = 0; mt < 3; ++mt)
    abp[mt] = dwh + (size_t)((mg * 3 + mt) * 32 + (lane & 31)) * 512 + ((lane >> 5) << 3);

  const int brow = pt * 32 + (lane & 31);
  const int bsw = (brow >> 1) & 3;
  int boff[2];
#pragma unroll
  for (int ks = 0; ks < 2; ++ks)
    boff[ks] = brow * 32 + (((ks * 2 + (lane >> 5)) ^ bsw)) * 8;

  f32x16 acc[3];
#pragma unroll
  for (int mt = 0; mt < 3; ++mt) acc[mt] = (f32x16)(0.0f);
  f16x8 A[2][3][2];
  f16x8 qd[2];

  qd[0] = *(const f16x8*)(qsrc);
#pragma unroll
  for (int mt = 0; mt < 3; ++mt)
#pragma unroll
    for (int ks = 0; ks < 2; ++ks)
      A[0][mt][ks] = *(const f16x8*)(abp[mt] + ks * 16);
  *(f16x8*)&QB[0][ldsW] = qd[0];
  qd[1] = *(const f16x8*)(qsrc + 32);
  __syncthreads();

#pragma unroll
  for (int ch = 0; ch < 16; ++ch) {
    const int par = ch & 1;
    if (ch < 15) {
      *(f16x8*)&QB[par ^ 1][ldsW] = qd[(ch + 1) & 1];
#pragma unroll
      for (int mt = 0; mt < 3; ++mt)
#pragma unroll
        for (int ks = 0; ks < 2; ++ks)
          A[par ^ 1][mt][ks] = *(const f16x8*)(abp[mt] + (ch + 1) * 32 + ks * 16);
    }
    if (ch < 14) qd[ch & 1] = *(const f16x8*)(qsrc + (ch + 2) * 32);
    const f16x8 B0 = *(const f16x8*)&QB[par][boff[0]];
    const f16x8 B1 = *(const f16x8*)&QB[par][boff[1]];
#pragma unroll
    for (int mt = 0; mt < 3; ++mt) {
      acc[mt] = __builtin_amdgcn_mfma_f32_32x32x16_f16(A[par][mt][0], B0, acc[mt], 0, 0, 0);
      acc[mt] = __builtin_amdgcn_mfma_f32_32x32x16_f16(A[par][mt][1], B1, acc[mt], 0, 0, 0);
    }
    __syncthreads();
  }

  const float b0 = db[0], b1 = db[1], b2 = db[2];
  const int pix = pixbase + pt * 32 + (lane & 31);
  const int i = pix >> 5, j = pix & 31;
#pragma unroll
  for (int mt = 0; mt < 3; ++mt) {
    const int m0 = (mg * 3 + mt) * 32;
#pragma unroll
    for (int r = 0; r < 16; ++r) {
      const int m = m0 + (r & 3) + ((r >> 2) << 3) + ((lane >> 5) << 2);
      const int c = m >> 6, ki = (m >> 3) & 7, kj = m & 7;
      const float bias = (c == 0) ? b0 : ((c == 1) ? b1 : b2);
      out[(((size_t)b * 3 + c) * 256 + i * 8 + 7 - ki) * 256 + j * 8 + 7 - kj] = acc[mt][r] + bias;
    }
  }
}

// ---------------- decode fallback: fp32 VALU (if ws too small) --------------
__global__ __launch_bounds__(256) void k_decode(const float* __restrict__ dw,
                                                const float* __restrict__ db,
                                                float* out) {
  __shared__ __align__(16) float Qs[32][132];
  __shared__ __align__(16) float Ws3[32][68];
  const int n0 = blockIdx.x * 128;
  const int b = n0 / PIXB, pixbase = n0 % PIXB;
  const int mt = blockIdx.y;
  const int t = threadIdx.x;
  const int pg = t & 31, ck = t >> 5;
  float acc[4][8];
#pragma unroll
  for (int p = 0; p < 4; ++p)
#pragma unroll
    for (int k = 0; k < 8; ++k) acc[p][k] = 0.f;
  for (int dc = 0; dc < 16; ++dc) {
#pragma unroll
    for (int ii = 0; ii < 4; ++ii) {
      const int id = t + ii * 256;
      const int dd = id >> 5, p4 = id & 31;
      *reinterpret_cast<float4*>(&Qs[dd][p4 * 4]) =
        *reinterpret_cast<const float4*>(&out[OFF_E + ((size_t)b * 512 + dc * 32 + dd) * 1024 + pixbase + p4 * 4]);
    }
#pragma unroll
    for (int ii = 0; ii < 2; ++ii) {
      const int id = t + ii * 256;
      const int dd = id >> 4, m4 = id & 15;
      *reinterpret_cast<float4*>(&Ws3[dd][m4 * 4]) =
        *reinterpret_cast<const float4*>(&dw[(size_t)(dc * 32 + dd) * 192 + mt * 64 + m4 * 4]);
    }
    __syncthreads();
#pragma unroll
    for (int dd = 0; dd < 32; ++dd) {
      const float4 qv = *reinterpret_cast<const float4*>(&Qs[dd][pg * 4]);
      const float4 wa = *reinterpret_cast<const float4*>(&Ws3[dd][ck * 8]);
      const float4 wb = *reinterpret_cast<const float4*>(&Ws3[dd][ck * 8 + 4]);
      const float q[4] = {qv.x, qv.y, qv.z, qv.w};
      const float wv[8] = {wa.x, wa.y, wa.z, wa.w, wb.x, wb.y, wb.z, wb.w};
#pragma unroll
      for (int p = 0; p < 4; ++p)
#pragma unroll
        for (int k = 0; k < 8; ++k) acc[p][k] = fmaf(q[p], wv[k], acc[p][k]);
    }
    __syncthreads();
  }
  const int ckg = mt * 8 + ck;
  const int c = ckg >> 3, ki = ckg & 7;
  const float bias = db[c];
#pragma unroll
  for (int p = 0; p < 4; ++p) {
    const int pix = pixbase + pg * 4 + p;
    const int i = pix >> 5, j = pix & 31;
    const size_t base = (((size_t)b * 3 + c) * 256 + i * 8 + 7 - ki) * 256 + j * 8;
#pragma unroll
    for (int kj = 0; kj < 8; ++kj) out[base + 7 - kj] = acc[p][kj] + bias;
  }
}

extern "C" void kernel_launch(void* const* d_in, const int* in_sizes, int n_in,
                              void* d_out, int out_size, void* d_ws, size_t ws_size,
                              hipStream_t stream) {
  const float* x     = (const float*)d_in[0];
  const float* enc_w = (const float*)d_in[1];
  const float* enc_b = (const float*)d_in[2];
  const float* dec_w = (const float*)d_in[3];
  const float* dec_b = (const float*)d_in[4];
  const float* emb_w = (const float*)d_in[5];
  float* out = (float*)d_out;
  float* w2 = (float*)d_ws;                              // 2KB
  _Float16* wrow = (_Float16*)((char*)d_ws + 2048);      // 512KB
  _Float16* dwh  = (_Float16*)((char*)d_ws + 2048 + 524288);  // 192KB
  const int do_aux = (ws_size >= (size_t)(2048 + 524288 + 196608)) ? 1 : 0;
  _Float16* wq  = (_Float16*)d_out;                      // 1MB in recon region
  _Float16* aq  = (_Float16*)((char*)d_out + 2097152);   // 384KB in recon region
  _Float16* zq2 = (_Float16*)((char*)d_out + 92274688);  // 67MB in emb region

  k_prep<<<122, 256, 0, stream>>>(emb_w, dec_w, enc_w, wq, w2, aq, wrow, dwh, do_aux);
  k_encmfma<<<512, 512, 0, stream>>>(x, aq, enc_b, zq2, out);
  k_dist<<<512, 512, 0, stream>>>(wq, zq2, w2, out);
  k_gather<<<1024, 256, 0, stream>>>(emb_w, out);
  if (do_aux)
    k_decmfma<<<256, 512, 0, stream>>>(wrow, dwh, dec_b, out);
  else
    k_decode<<<dim3(256, 3), 256, 0, stream>>>(dec_w, dec_b, out);
}

// Round 12
// 192.775 us; speedup vs baseline: 2.0755x; 1.0809x over previous
//
#include <hip/hip_runtime.h>
#include <cfloat>

#define PIXB 1024
static const size_t OFF_Z = 6291456;   // recon = 32*3*256*256
static const size_t OFF_E = 23068672;  // OFF_Z + 32*512*32*32
static const size_t OFF_A = 39845888;  // OFF_E + 32*512*32*32

typedef __attribute__((address_space(1))) const unsigned int cg_u32;
typedef __attribute__((address_space(3))) unsigned int l_u32;
typedef _Float16 f16x8 __attribute__((ext_vector_type(8)));
typedef float f32x16 __attribute__((ext_vector_type(16)));

#define SPLIT_SCALE 4096.0f
#define SPLIT_INV   (1.0f / 4096.0f)

#define GL16(srcp, dstp) __builtin_amdgcn_global_load_lds((cg_u32*)(srcp), (l_u32*)(dstp), 16, 0, 0)

// ---------------- prep: all weight-side tables ------------------------------
// bx 0..31  : wq chunk-images (k_dist A, swizzled; recon region)
// bx 32..33 : w2 (d_ws)
// bx 34..45 : aq chunk-images (encode A, swizzled; recon region +2MB)
// bx 46..109: wrow [code][d] fp16 (decode gather table, d_ws)  [do_aux]
// bx 110..121: dwh [m 192][d] fp16 (decode A, d_ws)            [do_aux]
__global__ __launch_bounds__(256) void k_prep(const float* __restrict__ W,
                                              const float* __restrict__ dw,
                                              const float* __restrict__ ew,
                                              _Float16* __restrict__ wq,
                                              float* __restrict__ w2,
                                              _Float16* __restrict__ aq,
                                              _Float16* __restrict__ wrow,
                                              _Float16* __restrict__ dwh,
                                              int do_aux) {
  const int t = threadIdx.x;
  const int bx = blockIdx.x;
  __shared__ float T[64][65];
  __shared__ float T2[128][65];
  if (bx < 32) {
    __shared__ float TS[32][260];
    const int cp = bx >> 4, ch = bx & 15;
#pragma unroll
    for (int i = 0; i < 32; ++i)
      TS[i][t] = W[(size_t)(ch * 32 + i) * 512 + cp * 256 + t];
    __syncthreads();
#pragma unroll
    for (int j = 0; j < 4; ++j) {
      const int u = j * 256 + t;
      const int c = u >> 2, slot = u & 3;
      const int se = slot ^ ((c >> 1) & 3);
      f16x8 h, l;
#pragma unroll
      for (int jj = 0; jj < 8; ++jj) {
        const float v = TS[slot * 8 + jj][c];
        const _Float16 hh = (_Float16)v;
        h[jj] = hh;
        l[jj] = (_Float16)((v - (float)hh) * SPLIT_SCALE);
      }
      _Float16* base = wq + cp * 262144 + ch * 16384 + c * 32 + se * 8;
      *(f16x8*)(base) = h;
      *(f16x8*)(base + 8192) = l;
    }
    return;
  }
  if (bx < 34) {
    const int k = (bx - 32) * 256 + t;
    float acc = 0.f;
    for (int d = 0; d < 512; ++d) { const float v = W[(size_t)d * 512 + k]; acc = fmaf(v, v, acc); }
    w2[k] = acc;
    return;
  }
  if (bx < 46) {                 // aq: enc_w [c][192] -> chunk images
    const int ch = bx - 34;
#pragma unroll
    for (int cc = 0; cc < 2; ++cc) {
      const int c = cc * 256 + t;
      const float* src = ew + (size_t)c * 192 + ch * 16;
#pragma unroll
      for (int slot = 0; slot < 2; ++slot) {
        f16x8 h, l;
#pragma unroll
        for (int j = 0; j < 8; ++j) {
          const float v = src[slot * 8 + j];
          const _Float16 hh = (_Float16)v;
          h[j] = hh;
          l[j] = (_Float16)((v - (float)hh) * SPLIT_SCALE);
        }
        const int se = slot ^ ((c >> 2) & 1);
        _Float16* dst = aq + (size_t)ch * 16384 + c * 16 + se * 8;
        *(f16x8*)dst = h;
        *(f16x8*)(dst + 8192) = l;
      }
    }
    return;
  }
  if (!do_aux) return;
  if (bx < 110) {                // wrow: transpose W [d][c] -> fp16 [c][d]
    const int id = bx - 46;
    const int c0 = (id & 7) * 64, d0 = (id >> 3) * 64;
#pragma unroll
    for (int i = 0; i < 16; ++i) {
      const int dl = i * 4 + (t >> 6);
      T[dl][t & 63] = W[(size_t)(d0 + dl) * 512 + c0 + (t & 63)];
    }
    __syncthreads();
#pragma unroll
    for (int i = 0; i < 16; ++i) {
      const int cl = i * 4 + (t >> 6);
      const int dl = t & 63;
      wrow[(size_t)(c0 + cl) * 512 + d0 + dl] = (_Float16)T[dl][cl];
    }
    return;
  }
  {                              // dwh: transpose dec_w [d][m] -> fp16 [m][d]
    const int id = bx - 110;
    const int m0 = (id % 3) * 64, d0 = (id / 3) * 128;
#pragma unroll
    for (int i = 0; i < 32; ++i) {
      const int idx = i * 256 + t;
      const int dl = idx >> 6, ml = idx & 63;
      T2[dl][ml] = dw[(size_t)(d0 + dl) * 192 + m0 + ml];
    }
    __syncthreads();
#pragma unroll
    for (int i = 0; i < 32; ++i) {
      const int idx = i * 256 + t;
      const int ml = idx >> 7, dl = idx & 127;
      dwh[(size_t)(m0 + ml) * 512 + d0 + dl] = (_Float16)T2[dl][ml];
    }
  }
}

// -------- encode via MFMA (fp16 2-split, 3 products), counted-vmcnt ---------
// As round 11, minus the zq2 epilogue: dist now reads z_e fp32 directly.
__global__ __launch_bounds__(512) void k_encmfma(const float* __restrict__ x,
                                                 const _Float16* __restrict__ aq,
                                                 const float* __restrict__ eb,
                                                 float* __restrict__ out) {
  __shared__ __align__(16) unsigned char CB[131072];  // A 3x32KB | B 4x8KB
  __shared__ float ebL[512];
  const int t = threadIdx.x;
  ebL[t] = eb[t];
  const int w = t >> 6, lane = t & 63;
  const int wc = w & 3, wp = w >> 2;
  const int n0 = blockIdx.x * 64;
  const int b = n0 >> 10, pixbase = n0 & 1023;
  const int i0 = pixbase >> 5;
  const int row = lane & 31, hi = lane >> 5;

  int ab[4];
#pragma unroll
  for (int ct = 0; ct < 4; ++ct) {
    const int c = wc * 128 + ct * 32 + row;
    ab[ct] = c * 32 + ((hi ^ ((c >> 2) & 1)) << 4);
  }
  const int u = t & 255, srow = u >> 6, vsl = u & 63;
  const int csrc = vsl ^ ((vsl >> 3) & 1);
  const float* xb = x + ((size_t)b * 3 * 256 + (i0 + (srow >> 1)) * 8 + (srow & 1)) * 256 + csrc * 4;
  const int bv0 = (((2 * row) ^ ((row >> 2) & 1)) << 4);
  const int bv1 = (((2 * row + 1) ^ ((row >> 2) & 1)) << 4);
  const int brb = wp * 4096 + (wp * 2 + hi) * 1024;

  f32x16 accA[4], accB[4];
#pragma unroll
  for (int ct = 0; ct < 4; ++ct) { accA[ct] = (f32x16)(0.0f); accB[ct] = (f32x16)(0.0f); }

#define STAGE_A(chv) { const _Float16* as_ = aq + (size_t)(chv) * 16384 + t * 8;            \
    char* ad_ = (char*)CB + ((chv) % 3) * 32768 + t * 16;                                   \
    GL16(as_, ad_); GL16(as_ + 4096, ad_ + 8192);                                           \
    GL16(as_ + 8192, ad_ + 16384); GL16(as_ + 12288, ad_ + 24576); }
#define STAGE_B(chv) GL16(xb + (((chv) >> 2) * 65536 + ((chv) & 3) * 512),                  \
                          (char*)CB + 98304 + (((chv) & 3)) * 8192 + t * 16)
#define ECOMP(chv)                                                                          \
  { const char* abuf = (const char*)CB + ((chv) % 3) * 32768;                               \
    const char* bbuf = (const char*)CB + 98304 + ((chv) & 3) * 8192 + brb;                  \
    const float4 xa = *(const float4*)(bbuf + bv0);                                         \
    const float4 xc = *(const float4*)(bbuf + bv1);                                         \
    const float xs[8] = {xa.x, xa.y, xa.z, xa.w, xc.x, xc.y, xc.z, xc.w};                   \
    f16x8 Bh, Bl;                                                                           \
    _Pragma("unroll") for (int q = 0; q < 8; ++q) {                                         \
      const _Float16 hh = (_Float16)xs[q];                                                  \
      Bh[q] = hh; Bl[q] = (_Float16)((xs[q] - (float)hh) * SPLIT_SCALE); }                  \
    __builtin_amdgcn_s_setprio(1);                                                          \
    _Pragma("unroll") for (int ct_ = 0; ct_ < 4; ++ct_) {                                   \
      const f16x8 Ah = *(const f16x8*)(abuf + ab[ct_]);                                     \
      const f16x8 Al = *(const f16x8*)(abuf + 16384 + ab[ct_]);                             \
      accA[ct_] = __builtin_amdgcn_mfma_f32_32x32x16_f16(Ah, Bh, accA[ct_], 0, 0, 0);       \
      accB[ct_] = __builtin_amdgcn_mfma_f32_32x32x16_f16(Ah, Bl, accB[ct_], 0, 0, 0);       \
      accB[ct_] = __builtin_amdgcn_mfma_f32_32x32x16_f16(Al, Bh, accB[ct_], 0, 0, 0); }     \
    __builtin_amdgcn_s_setprio(0); }
#define EPHASE(chv, waitlit)                                                                \
  { asm volatile("s_waitcnt vmcnt(" #waitlit ")" ::: "memory");                             \
    __builtin_amdgcn_sched_barrier(0);                                                      \
    __builtin_amdgcn_s_barrier();                                                           \
    ECOMP(chv);                                                                             \
    __builtin_amdgcn_s_barrier(); }

  STAGE_A(0); STAGE_B(0);
  STAGE_A(1); STAGE_B(1);
  STAGE_B(2);
#pragma unroll 1
  for (int ch = 0; ch < 9; ++ch) {
    STAGE_A(ch + 2);
    STAGE_B(ch + 3);
    EPHASE(ch, 11);
  }
  STAGE_A(11);
  EPHASE(9, 10);
  EPHASE(10, 5);
  EPHASE(11, 0);
#undef STAGE_A
#undef STAGE_B
#undef ECOMP
#undef EPHASE

  // ---- epilogue: z_e fp32 (coalesced 256B/row across lanes) ----
  const int pl = wp * 32 + row;
#pragma unroll
  for (int ct = 0; ct < 4; ++ct) {
#pragma unroll
    for (int r = 0; r < 16; ++r) {
      const int c = wc * 128 + ct * 32 + (r & 3) + ((r >> 2) << 3) + (hi << 2);
      out[OFF_Z + ((size_t)(b * 512 + c)) * 1024 + pixbase + pl] =
          fmaf(accB[ct][r], SPLIT_INV, accA[ct][r]) + ebL[c];
    }
  }
}

// -------- distance + argmin + gather: counted-vmcnt MFMA, z_e direct --------
// z staged as fp32 [d 32][pix 64] chunks straight from the z_e output (L3-hot)
// and split to fp16 in-register (identical fp32 inputs -> identical splits ->
// accumulators bit-identical to rounds 10/11). Same 5 loads/thread/chunk ->
// same vmcnt literals. Epilogue: argmin + fused emb gather-write.
__global__ __launch_bounds__(512) void k_dist(const _Float16* __restrict__ wq,
                                              const float* __restrict__ Wc,
                                              const float* __restrict__ w2ws,
                                              float* __restrict__ out) {
  __shared__ __align__(16) unsigned char CB[131072];  // W 3x32KB | z 4x8KB
  __shared__ float WV[512];
  __shared__ int   WI[512];
  __shared__ int   IDX[64];
  const int t = threadIdx.x;
  const int w = t >> 6, lane = t & 63;
  const int wc = w & 3, wp = w >> 2;
  const int n0 = blockIdx.x * 64;
  const int b = n0 >> 10, pixbase = n0 & 1023;
  const int row = lane & 31, hi = lane >> 5;
  const int pl = wp * 32 + row;

  int abase[2][2];
#pragma unroll
  for (int ct = 0; ct < 2; ++ct) {
    const int cl = wc * 64 + ct * 32 + row;
    const int sw = ((cl >> 1) & 3) << 4;
#pragma unroll
    for (int ks = 0; ks < 2; ++ks)
      abase[ct][ks] = cl * 64 + (((ks << 5) | (hi << 4)) ^ sw);
  }
  // z staging: thread t stages 16B of row (t>>4) of the [32][64] fp32 tile
  const float* zsrc = out + OFF_Z + ((size_t)(b * 512 + (t >> 4))) * 1024 + pixbase + (t & 15) * 4;

#define STAGE_W(cpv, chv)                                                        \
  { const _Float16* ws_ = wq + (cpv) * 262144 + (chv) * 16384 + t * 8;           \
    char* wd_ = (char*)CB + ((chv) % 3) * 32768 + t * 16;                        \
    GL16(ws_, wd_); GL16(ws_ + 4096, wd_ + 8192);                                \
    GL16(ws_ + 8192, wd_ + 16384); GL16(ws_ + 12288, wd_ + 24576); }
#define STAGE_Z(chv)                                                             \
  GL16(zsrc + (size_t)(chv) * 32768,                                             \
       (char*)CB + 98304 + ((chv) & 3) * 8192 + t * 16)
#define COMPUTE(chv)                                                             \
  { const char* wb_ = (const char*)CB + ((chv) % 3) * 32768;                     \
    const char* zb_ = (const char*)CB + 98304 + ((chv) & 3) * 8192;              \
    f16x8 Bh0, Bl0, Bh1, Bl1;                                                    \
    _Pragma("unroll") for (int q = 0; q < 8; ++q) {                              \
      const float f0 = *(const float*)(zb_ + (hi * 8 + q) * 256 + pl * 4);       \
      const _Float16 h0 = (_Float16)f0;                                          \
      Bh0[q] = h0; Bl0[q] = (_Float16)((f0 - (float)h0) * SPLIT_SCALE);          \
      const float f1 = *(const float*)(zb_ + (16 + hi * 8 + q) * 256 + pl * 4);  \
      const _Float16 h1 = (_Float16)f1;                                          \
      Bh1[q] = h1; Bl1[q] = (_Float16)((f1 - (float)h1) * SPLIT_SCALE); }        \
    __builtin_amdgcn_s_setprio(1);                                               \
    _Pragma("unroll")                                                            \
    for (int ct_ = 0; ct_ < 2; ++ct_) {                                          \
      const f16x8 Ah0 = *(const f16x8*)(wb_ + abase[ct_][0]);                    \
      const f16x8 Al0 = *(const f16x8*)(wb_ + 16384 + abase[ct_][0]);            \
      const f16x8 Ah1 = *(const f16x8*)(wb_ + abase[ct_][1]);                    \
      const f16x8 Al1 = *(const f16x8*)(wb_ + 16384 + abase[ct_][1]);            \
      accA[ct_] = __builtin_amdgcn_mfma_f32_32x32x16_f16(Ah0, Bh0, accA[ct_], 0, 0, 0); \
      accB[ct_] = __builtin_amdgcn_mfma_f32_32x32x16_f16(Ah0, Bl0, accB[ct_], 0, 0, 0); \
      accB[ct_] = __builtin_amdgcn_mfma_f32_32x32x16_f16(Al0, Bh0, accB[ct_], 0, 0, 0); \
      accA[ct_] = __builtin_amdgcn_mfma_f32_32x32x16_f16(Ah1, Bh1, accA[ct_], 0, 0, 0); \
      accB[ct_] = __builtin_amdgcn_mfma_f32_32x32x16_f16(Ah1, Bl1, accB[ct_], 0, 0, 0); \
      accB[ct_] = __builtin_amdgcn_mfma_f32_32x32x16_f16(Al1, Bh1, accB[ct_], 0, 0, 0); \
    }                                                                            \
    __builtin_amdgcn_s_setprio(0); }
#define PHASE(chv, waitlit)                                                      \
  { asm volatile("s_waitcnt vmcnt(" #waitlit ")" ::: "memory");                  \
    __builtin_amdgcn_sched_barrier(0);                                           \
    __builtin_amdgcn_s_barrier();                                                \
    COMPUTE(chv);                                                                \
    __builtin_amdgcn_s_barrier(); }

  float bv = FLT_MAX; int bi = 0x7fffffff;

#pragma unroll 1
  for (int cp = 0; cp < 2; ++cp) {
    f32x16 accA[2], accB[2];
#pragma unroll
    for (int ct = 0; ct < 2; ++ct) { accA[ct] = (f32x16)(0.0f); accB[ct] = (f32x16)(0.0f); }
    STAGE_W(cp, 0); STAGE_Z(0);
    STAGE_W(cp, 1); STAGE_Z(1);
    STAGE_Z(2);
#pragma unroll 1
    for (int ch = 0; ch < 13; ++ch) {
      STAGE_W(cp, ch + 2);
      STAGE_Z(ch + 3);
      PHASE(ch, 11);
    }
    STAGE_W(cp, 15);
    PHASE(13, 10);
    PHASE(14, 5);
    PHASE(15, 0);

#pragma unroll
    for (int ct = 0; ct < 2; ++ct) {
#pragma unroll
      for (int r = 0; r < 16; ++r) {
        const int code = cp * 256 + wc * 64 + ct * 32 +
                         ((r & 3) + ((r >> 2) << 3) + (hi << 2));
        const float zw = fmaf(accB[ct][r], SPLIT_INV, accA[ct][r]);
        const float d2 = fmaf(-2.f, zw, w2ws[code]);
        if (d2 < bv || (d2 == bv && code < bi)) { bv = d2; bi = code; }
      }
    }
  }
#undef STAGE_W
#undef STAGE_Z
#undef COMPUTE
#undef PHASE

  WV[w * 64 + lane] = bv;
  WI[w * 64 + lane] = bi;
  __syncthreads();
  if (t < 64) {
    const int pw = t >> 5;
    float fbv = FLT_MAX; int fbi = 0x7fffffff;
#pragma unroll
    for (int wcc = 0; wcc < 4; ++wcc)
#pragma unroll
      for (int hh = 0; hh < 2; ++hh) {
        const int li = (pw * 4 + wcc) * 64 + (t & 31) + hh * 32;
        const float v = WV[li];
        const int ii = WI[li];
        if (v < fbv || (v == fbv && ii < fbi)) { fbv = v; fbi = ii; }
      }
    out[OFF_A + n0 + t] = (float)fbi;
    IDX[t] = fbi;
  }
  __syncthreads();

  // ---- fused gather: emb[d][pix] = W[d][argmin[pix]] ----
  const int pix = t & 63;
  const int kidx = IDX[pix];
  for (int d = t >> 6; d < 512; d += 8)
    out[OFF_E + ((size_t)(b * 512 + d)) * 1024 + pixbase + pix] = Wc[(size_t)d * 512 + kidx];
}

// -------- decode via single-fp16 MFMA (q in (-0.04,0.04), err ~2e-5) --------
__global__ __launch_bounds__(512) void k_decmfma(const _Float16* __restrict__ wrow,
                                                 const _Float16* __restrict__ dwh,
                                                 const float* __restrict__ db,
                                                 float* __restrict__ out) {
  __shared__ __align__(16) _Float16 QB[2][4096];
  __shared__ int KIDX[128];
  const int t = threadIdx.x;
  const int w = t >> 6, lane = t & 63;
  const int pt = w & 3, mg = w >> 2;
  const int blk = blockIdx.x;
  const int b = blk >> 3;
  const int pixbase = (blk & 7) * 128;
  if (t < 128) KIDX[t] = (int)out[OFF_A + b * 1024 + pixbase + t];
  __syncthreads();
  const int pixS = t >> 2, slotS = t & 3;
  const _Float16* qsrc = wrow + (size_t)KIDX[pixS] * 512 + slotS * 8;
  const int ldsW = pixS * 32 + (slotS ^ ((pixS >> 1) & 3)) * 8;

  const _Float16* abp[3];
#pragma unroll
  for (int mt = 0; mt < 3; ++mt)
    abp[mt] = dwh + (size_t)((mg * 3 + mt) * 32 + (lane & 31)) * 512 + ((lane >> 5) << 3);

  const int brow = pt * 32 + (lane & 31);
  const int bsw = (brow >> 1) & 3;
  int boff[2];
#pragma unroll
  for (int ks = 0; ks < 2; ++ks)
    boff[ks] = brow * 32 + (((ks * 2 + (lane >> 5)) ^ bsw)) * 8;

  f32x16 acc[3];
#pragma unroll
  for (int mt = 0; mt < 3; ++mt) acc[mt] = (f32x16)(0.0f);
  f16x8 A[2][3][2];
  f16x8 qd[2];

  qd[0] = *(const f16x8*)(qsrc);
#pragma unroll
  for (int mt = 0; mt < 3; ++mt)
#pragma unroll
    for (int ks = 0; ks < 2; ++ks)
      A[0][mt][ks] = *(const f16x8*)(abp[mt] + ks * 16);
  *(f16x8*)&QB[0][ldsW] = qd[0];
  qd[1] = *(const f16x8*)(qsrc + 32);
  __syncthreads();

#pragma unroll
  for (int ch = 0; ch < 16; ++ch) {
    const int par = ch & 1;
    if (ch < 15) {
      *(f16x8*)&QB[par ^ 1][ldsW] = qd[(ch + 1) & 1];
#pragma unroll
      for (int mt = 0; mt < 3; ++mt)
#pragma unroll
        for (int ks = 0; ks < 2; ++ks)
          A[par ^ 1][mt][ks] = *(const f16x8*)(abp[mt] + (ch + 1) * 32 + ks * 16);
    }
    if (ch < 14) qd[ch & 1] = *(const f16x8*)(qsrc + (ch + 2) * 32);
    const f16x8 B0 = *(const f16x8*)&QB[par][boff[0]];
    const f16x8 B1 = *(const f16x8*)&QB[par][boff[1]];
#pragma unroll
    for (int mt = 0; mt < 3; ++mt) {
      acc[mt] = __builtin_amdgcn_mfma_f32_32x32x16_f16(A[par][mt][0], B0, acc[mt], 0, 0, 0);
      acc[mt] = __builtin_amdgcn_mfma_f32_32x32x16_f16(A[par][mt][1], B1, acc[mt], 0, 0, 0);
    }
    __syncthreads();
  }

  const float b0 = db[0], b1 = db[1], b2 = db[2];
  const int pix = pixbase + pt * 32 + (lane & 31);
  const int i = pix >> 5, j = pix & 31;
#pragma unroll
  for (int mt = 0; mt < 3; ++mt) {
    const int m0 = (mg * 3 + mt) * 32;
#pragma unroll
    for (int r = 0; r < 16; ++r) {
      const int m = m0 + (r & 3) + ((r >> 2) << 3) + ((lane >> 5) << 2);
      const int c = m >> 6, ki = (m >> 3) & 7, kj = m & 7;
      const float bias = (c == 0) ? b0 : ((c == 1) ? b1 : b2);
      out[(((size_t)b * 3 + c) * 256 + i * 8 + 7 - ki) * 256 + j * 8 + 7 - kj] = acc[mt][r] + bias;
    }
  }
}

// ---------------- decode fallback: fp32 VALU (if ws too small) --------------
__global__ __launch_bounds__(256) void k_decode(const float* __restrict__ dw,
                                                const float* __restrict__ db,
                                                float* out) {
  __shared__ __align__(16) float Qs[32][132];
  __shared__ __align__(16) float Ws3[32][68];
  const int n0 = blockIdx.x * 128;
  const int b = n0 / PIXB, pixbase = n0 % PIXB;
  const int mt = blockIdx.y;
  const int t = threadIdx.x;
  const int pg = t & 31, ck = t >> 5;
  float acc[4][8];
#pragma unroll
  for (int p = 0; p < 4; ++p)
#pragma unroll
    for (int k = 0; k < 8; ++k) acc[p][k] = 0.f;
  for (int dc = 0; dc < 16; ++dc) {
#pragma unroll
    for (int ii = 0; ii < 4; ++ii) {
      const int id = t + ii * 256;
      const int dd = id >> 5, p4 = id & 31;
      *reinterpret_cast<float4*>(&Qs[dd][p4 * 4]) =
        *reinterpret_cast<const float4*>(&out[OFF_E + ((size_t)b * 512 + dc * 32 + dd) * 1024 + pixbase + p4 * 4]);
    }
#pragma unroll
    for (int ii = 0; ii < 2; ++ii) {
      const int id = t + ii * 256;
      const int dd = id >> 4, m4 = id & 15;
      *reinterpret_cast<float4*>(&Ws3[dd][m4 * 4]) =
        *reinterpret_cast<const float4*>(&dw[(size_t)(dc * 32 + dd) * 192 + mt * 64 + m4 * 4]);
    }
    __syncthreads();
#pragma unroll
    for (int dd = 0; dd < 32; ++dd) {
      const float4 qv = *reinterpret_cast<const float4*>(&Qs[dd][pg * 4]);
      const float4 wa = *reinterpret_cast<const float4*>(&Ws3[dd][ck * 8]);
      const float4 wb = *reinterpret_cast<const float4*>(&Ws3[dd][ck * 8 + 4]);
      const float q[4] = {qv.x, qv.y, qv.z, qv.w};
      const float wv[8] = {wa.x, wa.y, wa.z, wa.w, wb.x, wb.y, wb.z, wb.w};
#pragma unroll
      for (int p = 0; p < 4; ++p)
#pragma unroll
        for (int k = 0; k < 8; ++k) acc[p][k] = fmaf(q[p], wv[k], acc[p][k]);
    }
    __syncthreads();
  }
  const int ckg = mt * 8 + ck;
  const int c = ckg >> 3, ki = ckg & 7;
  const float bias = db[c];
#pragma unroll
  for (int p = 0; p < 4; ++p) {
    const int pix = pixbase + pg * 4 + p;
    const int i = pix >> 5, j = pix & 31;
    const size_t base = (((size_t)b * 3 + c) * 256 + i * 8 + 7 - ki) * 256 + j * 8;
#pragma unroll
    for (int kj = 0; kj < 8; ++kj) out[base + 7 - kj] = acc[p][kj] + bias;
  }
}

extern "C" void kernel_launch(void* const* d_in, const int* in_sizes, int n_in,
                              void* d_out, int out_size, void* d_ws, size_t ws_size,
                              hipStream_t stream) {
  const float* x     = (const float*)d_in[0];
  const float* enc_w = (const float*)d_in[1];
  const float* enc_b = (const float*)d_in[2];
  const float* dec_w = (const float*)d_in[3];
  const float* dec_b = (const float*)d_in[4];
  const float* emb_w = (const float*)d_in[5];
  float* out = (float*)d_out;
  float* w2 = (float*)d_ws;                              // 2KB
  _Float16* wrow = (_Float16*)((char*)d_ws + 2048);      // 512KB
  _Float16* dwh  = (_Float16*)((char*)d_ws + 2048 + 524288);  // 192KB
  const int do_aux = (ws_size >= (size_t)(2048 + 524288 + 196608)) ? 1 : 0;
  _Float16* wq  = (_Float16*)d_out;                      // 1MB in recon region
  _Float16* aq  = (_Float16*)((char*)d_out + 2097152);   // 384KB in recon region

  k_prep<<<122, 256, 0, stream>>>(emb_w, dec_w, enc_w, wq, w2, aq, wrow, dwh, do_aux);
  k_encmfma<<<512, 512, 0, stream>>>(x, aq, enc_b, out);
  k_dist<<<512, 512, 0, stream>>>(wq, emb_w, w2, out);
  if (do_aux)
    k_decmfma<<<256, 512, 0, stream>>>(wrow, dwh, dec_b, out);
  else
    k_decode<<<dim3(256, 3), 256, 0, stream>>>(dec_w, dec_b, out);
}